// Round 14
// baseline (941.003 us; speedup 1.0000x reference)
//
#include <hip/hip_runtime.h>
#include <hip/hip_bf16.h>
#include <math.h>

// Sizes fixed by the problem
#define BB 32
#define TT 128
#define KK 256
#define HH 512
#define VV 10000
#define VP 10240
#define BT 4096           // B*T
#define HLOG2PI 0.91893853320467274178f
#define FMSHIFT 16.0f     // fixed LSE shift for bounded-logit comps (|u| <= ~10)

// ---- workspace layout (float offsets) ----
// z       : 0          1048576   (dead — gx now fused into k_embed)
// qz      : 1048576    4096
// hb      : 1052672    1048576 floats worth = BT*H bf16 (ushort)
// zb      : 2101248    524288 floats worth  = BT*K bf16 (ushort)
// gx      : 3149824    4096
// region  : 3252224    13117440
//  phase 1 (lstm): xp(0..8388608) wpIF(+8388608) wpGO(+8650752)
//                  hpk(+8912896, 1048576 dwords) wb(+9961472, 524288 ushorts)
//  phase 2 (scores), overlaying dead xp: Pb / Qb / Gb / part / psum / cv

typedef short bf16x8 __attribute__((ext_vector_type(8)));
typedef float f32x4 __attribute__((ext_vector_type(4)));

__device__ __forceinline__ float softplus_b(float x) {
    float ax = fabsf(x);
    return fmaxf(x, 0.0f) + log2f(1.0f + exp2f(-ax));
}
__device__ __forceinline__ float sigm(float x) { return 1.0f / (1.0f + expf(-x)); }
// fast variants for the LSTM serial gate path (bf16-level accuracy is plenty)
__device__ __forceinline__ float fsigm(float x) { return 1.0f / (1.0f + __expf(-x)); }
__device__ __forceinline__ float ftanh(float x) {
    float e = __expf(2.0f * x);
    return 1.0f - 2.0f / (e + 1.0f);
}
__device__ __forceinline__ unsigned short f2bf(float f) {
    unsigned u = __float_as_uint(f);
    u += 0x7FFFu + ((u >> 16) & 1u);
    return (unsigned short)(u >> 16);
}
typedef _Float16 h2f16 __attribute__((ext_vector_type(2)));
__device__ __forceinline__ unsigned pkh2(float a, float b) {
    h2f16 h;
    h.x = (_Float16)a;
    h.y = (_Float16)b;
    return *(unsigned*)&h;
}
__device__ __forceinline__ float fdot2u(unsigned a, unsigned b, float c) {
    h2f16 ah = *(h2f16*)&a, bh = *(h2f16*)&b;
#if __has_builtin(__builtin_amdgcn_fdot2)
    return __builtin_amdgcn_fdot2(ah, bh, c, false);
#else
    return c + (float)ah.x * (float)bh.x + (float)ah.y * (float)bh.y;
#endif
}
// square a bf16x8 in-register: bf16->f32 is <<16; repack with v_cvt_pk_bf16_f32 (RNE)
__device__ __forceinline__ bf16x8 bsq(bf16x8 a) {
    union { bf16x8 v; unsigned w[4]; } u, r;
    u.v = a;
#pragma unroll
    for (int i = 0; i < 4; i++) {
        float lo = __uint_as_float(u.w[i] << 16);
        float hi = __uint_as_float(u.w[i] & 0xFFFF0000u);
        lo *= lo;
        hi *= hi;
        asm("v_cvt_pk_bf16_f32 %0, %1, %2" : "=v"(r.w[i]) : "v"(lo), "v"(hi));
    }
    return r.v;
}

// ---------------- 1) embedding -> zb (bf16), q_z_lp, gx (fused k_gx) ----------------
__global__ void k_embed(const int* __restrict__ x, const int* __restrict__ x_sl,
                        const float* __restrict__ eps, const float* __restrict__ emb,
                        const float* __restrict__ w_gen, const float* __restrict__ b_gen,
                        ushort* __restrict__ zb, float* __restrict__ qz,
                        float* __restrict__ gx) {
    int bt = blockIdx.x;
    int b = bt >> 7, t = bt & 127;
    int k = threadIdx.x;
    int xi = x[bt];
    float e1 = emb[xi * 512 + k];
    float sg = softplus_b(emb[xi * 512 + 256 + k]);
    float ep = eps[bt * 256 + k];
    float mk = (t < x_sl[b]) ? 1.f : 0.f;
    float zv = (e1 + sg * ep) * mk;
    zb[bt * 256 + k] = f2bf(zv);
    float q = -HLOG2PI - logf(sg) - 0.5f * ep * ep;
    float p = zv * w_gen[xi * 256 + k];  // fused k_gx dot term (f32 z in-register)
    __shared__ float red[256];
    red[k] = q;
    __syncthreads();
    for (int s = 128; s > 0; s >>= 1) {
        if (k < s) red[k] += red[k + s];
        __syncthreads();
    }
    if (k == 0) qz[bt] = red[0];
    __syncthreads();
    red[k] = p;
    __syncthreads();
    for (int s = 128; s > 0; s >>= 1) {
        if (k < s) red[k] += red[k + s];
        __syncthreads();
    }
    if (k == 0) gx[bt] = red[0] + b_gen[xi];
}

// ---------------- 2) x_proj via MFMA: xp = z_shift @ w_ih^T + b_ih + b_hh ----------------
__global__ __launch_bounds__(512) void k_xpm(const ushort* __restrict__ zb,
                                             const ushort* __restrict__ wb,
                                             const float* __restrict__ b_ih,
                                             const float* __restrict__ b_hh,
                                             float* __restrict__ xp) {
    __shared__ ushort zs[16384];  // [kc 8][256 granules of 16B], swizzled
    int tid = threadIdx.x;
    int mb = blockIdx.x >> 3;
    int nb = blockIdx.x & 7;
    int bt0 = mb << 6;
    int n0base = nb << 8;
    // stage A: z_shift rows bt0..bt0+63 (t==0 -> zeros), bf16 16B copies
    for (int i = tid; i < 2048; i += 512) {
        int quad = i & 3, row = (i >> 2) & 63, kc = i >> 8;  // kc 0..7
        int bt = bt0 + row;
        uint4 v = make_uint4(0, 0, 0, 0);
        if ((bt & 127) != 0)
            v = *(const uint4*)(zb + (size_t)(bt - 1) * 256 + kc * 32 + quad * 8);
        int g = (((row << 2) + (quad ^ (row & 3))) ^ (((row >> 2) & 1) << 2));
        *(uint4*)(zs + kc * 2048 + g * 8) = v;
    }
    __syncthreads();
    int w = tid >> 6, l = tid & 63;
    int quad = l >> 4, ln = l & 15;
    int n0 = n0base + (w << 5);
    const bf16x8* zs8 = (const bf16x8*)zs;
    const bf16x8* wb8 = (const bf16x8*)wb;
    int g0 = (((ln << 2) + (quad ^ (ln & 3))) ^ (((ln >> 2) & 1) << 2));
    int rb = (n0 + ln) << 5;  // wb granule row base (32 granules/row; ns adds 512)
    f32x4 acc[4][2];
#pragma unroll
    for (int ns = 0; ns < 2; ns++) {
        int col = n0 + (ns << 4) + ln;
        float bias = b_ih[col] + b_hh[col];
#pragma unroll
        for (int ms = 0; ms < 4; ms++) acc[ms][ns] = bias;
    }
#pragma unroll
    for (int kc = 0; kc < 8; kc++) {
        bf16x8 b0 = wb8[rb + (kc << 2) + quad];
        bf16x8 b1 = wb8[rb + 512 + (kc << 2) + quad];
#pragma unroll
        for (int ms = 0; ms < 4; ms++) {
            bf16x8 a = zs8[(kc << 8) + g0 + (ms << 6)];
            acc[ms][0] = __builtin_amdgcn_mfma_f32_16x16x32_bf16(a, b0, acc[ms][0], 0, 0, 0);
            acc[ms][1] = __builtin_amdgcn_mfma_f32_16x16x32_bf16(a, b1, acc[ms][1], 0, 0, 0);
        }
    }
    // write: row = 16*ms + 4*quad + r, col = n0 + 16*ns + ln
#pragma unroll
    for (int ms = 0; ms < 4; ms++)
#pragma unroll
        for (int ns = 0; ns < 2; ns++)
#pragma unroll
            for (int r = 0; r < 4; r++) {
                int row = bt0 + (ms << 4) + (quad << 2) + r;
                xp[(size_t)row * 2048 + n0 + (ns << 4) + ln] = acc[ms][ns][r];
            }
}

// ---------------- 2b) pack w_hh -> f16 pairs, layouts for k_lstm ----------------
__global__ __launch_bounds__(256) void k_wpack2(const float* __restrict__ w_hh,
                                                uint4* __restrict__ wpIF,
                                                uint4* __restrict__ wpGO) {
    int o = blockIdx.x * 256 + threadIdx.x;  // 0..65535
    if (blockIdx.y == 0) {
        int kq = o & 3, j_local = (o >> 2) & 63, q = (o >> 8) & 31, m = o >> 13;
        int jg = (m << 6) + j_local;
        int k = (kq << 7) + (q << 2);
        const float* wi = w_hh + (size_t)jg * 512 + k;
        const float* wf = w_hh + (size_t)(512 + jg) * 512 + k;
        uint4 u;
        u.x = pkh2(wi[0], wi[1]); u.y = pkh2(wi[2], wi[3]);
        u.z = pkh2(wf[0], wf[1]); u.w = pkh2(wf[2], wf[3]);
        wpIF[o] = u;
    } else {
        int q = o & 31, kq = (o >> 5) & 3, j_local = (o >> 7) & 63, m = o >> 13;
        int jg = (m << 6) + j_local;
        int k = (kq << 7) + (q << 2);
        const float* wg = w_hh + (size_t)(1024 + jg) * 512 + k;
        const float* wo = w_hh + (size_t)(1536 + jg) * 512 + k;
        uint4 u;
        u.x = pkh2(wg[0], wg[1]); u.y = pkh2(wg[2], wg[3]);
        u.z = pkh2(wo[0], wo[1]); u.w = pkh2(wo[2], wo[3]);
        wpGO[o] = u;
    }
}

// ---------------- 3) LSTM v6: 2 batches per block (sync amortization) ----------------
// r13 analysis: 5100 cyc/step = ~1150 compute + ~3900 cross-block sync (store
// visibility + poll RTT + 8-block skew). Weights (wif/wgo) depend only on the
// j-slice m, NOT the batch -> one block serves TWO batches with the same
// weights. 128 blocks = 8 m x 16 batch-pairs (b, b+16); per t-iteration the
// block processes b0 then b1: b1's producers stored ~half an iteration earlier
// so its poll hits immediately, and b0's wait amortizes over 2 batch-steps.
// XCD locality preserved: bids of a pair-group all == bgrp (mod 8).
// Inner q-loop kept BYTE-IDENTICAL to v5 (r10 spill lesson); bb loop unrolled,
// per-batch c state + hs2 dbuf. LDS 128K wif + [2][2][272] hbuf.
__global__ __launch_bounds__(256, 1) void k_lstm(const float* __restrict__ xp,
                                                 const uint4* __restrict__ wpIF,
                                                 const uint4* __restrict__ wpGO,
                                                 ushort* __restrict__ h_all,
                                                 unsigned* __restrict__ hpk) {
    extern __shared__ char smc[];
    uint4* wif = (uint4*)smc;                   // [q 32][wave-linear 256] = 128 KB
    unsigned* hs2 = (unsigned*)(smc + 131072);  // [bb 2][dbuf 2][272] dwords
    int bid = blockIdx.x;
    int bgrp = bid & 15;
    int m = bid >> 4;
    int tid = threadIdx.x;
    int w = tid >> 6, l = tid & 63;
    int jj = l >> 2, kq = l & 3;
    int j_local = (w << 4) + jj;
    int j_global = (m << 6) + j_local;
    const uint4* srcIF = wpIF + ((size_t)m << 13);
    for (int i = tid; i < 8192; i += 256) wif[i] = srcIF[i];
    uint4 wgo[32];
    const uint4* srcGO = wpGO + ((size_t)((((m << 6) + j_local) << 2) + kq) << 5);
#pragma unroll
    for (int q = 0; q < 32; q++) wgo[q] = srcGO[q];
    const uint4* wifp = wif + (w << 6) + l;
    int skslot = tid + ((tid >> 6) << 2);  // skewed write slot
    float c0 = 0.f, c1 = 0.f;
    __syncthreads();
    for (int t = 0; t < 128; t++) {
#pragma unroll
        for (int bb = 0; bb < 2; bb++) {
            int b = bgrp + (bb << 4);
            int bt = (b << 7) + t;
            float xg0 = 0.f, xg1 = 0.f, xg2 = 0.f, xg3 = 0.f;
            if (kq == 0) {  // prefetch xp before the poll (independent loads)
                const float* xpr = xp + (size_t)bt * 2048 + j_global;
                xg0 = xpr[0]; xg1 = xpr[512]; xg2 = xpr[1024]; xg3 = xpr[1536];
            }
            float a0 = 0.f, a1 = 0.f, a2 = 0.f, a3 = 0.f;
            if (t > 0) {
                const unsigned* src = hpk + ((size_t)(bt - 1) << 8);
                unsigned u;
                do {
                    u = __hip_atomic_load(src + tid, __ATOMIC_RELAXED, __HIP_MEMORY_SCOPE_AGENT);
                } while (u == 0xFFFFFFFFu);
                unsigned* hbuf = hs2 + ((bb << 1) | ((t - 1) & 1)) * 272;
                hbuf[skslot] = u;
                __syncthreads();
                const unsigned* hp2 = hbuf + kq * 68;
#pragma unroll
                for (int q = 0; q < 32; q++) {
                    uint4 A = wifp[q << 8];
                    uint4 B = wgo[q];
                    unsigned p0 = hp2[q << 1];
                    unsigned p1 = hp2[(q << 1) + 1];
                    a0 = fdot2u(A.x, p0, a0); a0 = fdot2u(A.y, p1, a0);
                    a1 = fdot2u(A.z, p0, a1); a1 = fdot2u(A.w, p1, a1);
                    a2 = fdot2u(B.x, p0, a2); a2 = fdot2u(B.y, p1, a2);
                    a3 = fdot2u(B.z, p0, a3); a3 = fdot2u(B.w, p1, a3);
                }
#pragma unroll
                for (int off = 1; off <= 2; off <<= 1) {
                    a0 += __shfl_xor(a0, off);
                    a1 += __shfl_xor(a1, off);
                    a2 += __shfl_xor(a2, off);
                    a3 += __shfl_xor(a3, off);
                }
            }
            float h = 0.f;
            if (kq == 0) {
                float c = bb ? c1 : c0;
                float g0 = xg0 + a0, g1 = xg1 + a1, g2 = xg2 + a2, g3 = xg3 + a3;
                c = fsigm(g1) * c + fsigm(g0) * ftanh(g2);
                h = fsigm(g3) * ftanh(c);
                if (bb) c1 = c; else c0 = c;
                h_all[(size_t)bt * 512 + j_global] = f2bf(h);  // bf16, read post-kernel
            }
            float hp = __shfl_xor(h, 4);  // leader jj even <- h of jj+1
            if (kq == 0 && (jj & 1) == 0) {
                unsigned u = pkh2(h, hp);
                __hip_atomic_store(hpk + ((size_t)bt << 8) + (m << 5) + (w << 3) + (jj >> 1),
                                   u, __ATOMIC_RELAXED, __HIP_MEMORY_SCOPE_AGENT);
            }
        }
    }
}

// ---------------- 4a) cast weights -> bf16 row-major [v][2^kshift granules] ----------------
__global__ __launch_bounds__(256) void k_pack_w(const float* __restrict__ src,
                                                ushort* __restrict__ dst, int kshift) {
    int o = blockIdx.x * 256 + threadIdx.x;  // one ushort4 unit
    int c = o & ((1 << kshift) - 1);
    int r = o >> kshift;
    ushort4 u = make_ushort4(0, 0, 0, 0);
    if (r < VV) {
        float4 v = *(const float4*)(src + ((size_t)r << (kshift + 2)) + (c << 2));
        u = make_ushort4(f2bf(v.x), f2bf(v.y), f2bf(v.z), f2bf(v.w));
    }
    *(ushort4*)(dst + ((size_t)o << 2)) = u;
}

// ---------------- 4b) Qb rows [2*iv*mu (256) | -iv (256)] bf16 + const_v ----------------
__global__ void k_pack_q(const float* __restrict__ emb, ushort* __restrict__ Qb,
                         float* __restrict__ cv) {
    int v = blockIdx.x, k = threadIdx.x;
    if (v >= VV) {
        Qb[((size_t)v << 9) + k] = 0;
        Qb[((size_t)v << 9) + 256 + k] = 0;
        if (k == 0) cv[v] = 0.f;
        return;
    }
    float mu = emb[(size_t)v * 512 + k];
    float sg = softplus_b(emb[(size_t)v * 512 + 256 + k]);
    float iv = 0.5f / (sg * sg);
    Qb[((size_t)v << 9) + k] = f2bf(2.f * iv * mu);
    Qb[((size_t)v << 9) + 256 + k] = f2bf(-iv);
    float ct = -HLOG2PI - logf(sg) - mu * mu * iv;
    __shared__ float red[256];
    red[k] = ct;
    __syncthreads();
    for (int s = 128; s > 0; s >>= 1) {
        if (k < s) red[k] += red[k + s];
        __syncthreads();
    }
    if (k == 0) cv[v] = red[0];
}

// ---------------- 6) fused scores v7: fixed-shift LSE for bounded comps ----------------
__global__ __launch_bounds__(512, 2) void k_scores(
    const ushort* __restrict__ hb, const ushort* __restrict__ zb,
    const ushort* __restrict__ Pb, const ushort* __restrict__ Qb,
    const ushort* __restrict__ Gb, const float* __restrict__ cv,
    const float* __restrict__ b_prior, const float* __restrict__ b_gen,
    float* __restrict__ part) {
    extern __shared__ ushort sm[];
    ushort* hT = sm;           // [kc 16][64 rows][32], swizzled granules = 64 KB
    ushort* fzT = sm + 32768;  // [kc 16][64 rows][32]: kc<8 z, kc>=8 z^2 = 64 KB
    int tid = threadIdx.x;
    int vs = blockIdx.x & 7;
    int mb = blockIdx.x >> 3;
    int bt0 = mb << 6;
    int vbase = vs * 1280;
    // stage h tile (64 x 512 bf16): pure 16B copies
    for (int i = tid; i < 4096; i += 512) {
        int quad = i & 3, row = (i >> 2) & 63, kc = i >> 8;
        uint4 v = *(const uint4*)(hb + (size_t)(bt0 + row) * 512 + kc * 32 + quad * 8);
        int g = (((row << 2) + (quad ^ (row & 3))) ^ (((row >> 2) & 1) << 2));
        *(uint4*)(hT + kc * 2048 + g * 8) = v;
    }
    // stage z (copy) + z^2 (bsq once per granule)
    for (int i = tid; i < 2048; i += 512) {
        int quad = i & 3, row = (i >> 2) & 63, kc = i >> 8;  // kc 0..7
        uint4 v = *(const uint4*)(zb + (size_t)(bt0 + row) * 256 + kc * 32 + quad * 8);
        int g = (((row << 2) + (quad ^ (row & 3))) ^ (((row >> 2) & 1) << 2));
        *(uint4*)(fzT + kc * 2048 + g * 8) = v;
        bf16x8 sq = bsq(*(bf16x8*)&v);
        *(uint4*)(fzT + (kc + 8) * 2048 + g * 8) = *(uint4*)&sq;
    }
    __syncthreads();
    int w = tid >> 6, l = tid & 63;
    int quad = l >> 4, ln = l & 15;
    int nq = w;  // wave: ALL 64 rows x cols nq*32..+32 per nt group
    const bf16x8* hT8 = (const bf16x8*)hT;
    const bf16x8* fz8 = (const bf16x8*)fzT;
    const bf16x8* Pb8 = (const bf16x8*)Pb;
    const bf16x8* Qb8 = (const bf16x8*)Qb;
    const bf16x8* Gb8 = (const bf16x8*)Gb;
    // ms=0 row = ln; ms adds 16 rows => granule g0 + 64*ms (swizzle-consistent)
    int g0 = (((ln << 2) + (quad ^ (ln & 3))) ^ (((ln >> 2) & 1) << 2));
    float Ls[3][16], Lm1[16];
#pragma unroll
    for (int c = 0; c < 3; c++)
#pragma unroll
        for (int r = 0; r < 16; r++) Ls[c][r] = 0.f;
#pragma unroll
    for (int r = 0; r < 16; r++) Lm1[r] = -1e30f;
#pragma unroll 1
    for (int nt = 0; nt < 5; nt++) {
        int n0 = vbase + (nt << 8) + (nq << 5);
        int rb = (n0 + ln) << 6;  // Pb/Qb granule row base (ns adds 1024)
        int rg = (n0 + ln) << 5;  // Gb granule row base (ns adds 512)
        __builtin_amdgcn_s_setprio(1);
        // ---- chain A: prior logits, h (K=512) vs Pb ----
        f32x4 accA[4][2];
#pragma unroll
        for (int ms = 0; ms < 4; ms++) { accA[ms][0] = 0.f; accA[ms][1] = 0.f; }
#pragma unroll 2
        for (int kc = 0; kc < 16; kc++) {
            bf16x8 b0 = Pb8[rb + (kc << 2) + quad];
            bf16x8 b1 = Pb8[rb + 1024 + (kc << 2) + quad];
#pragma unroll
            for (int ms = 0; ms < 4; ms++) {
                bf16x8 a = hT8[(kc << 8) + g0 + (ms << 6)];
                accA[ms][0] = __builtin_amdgcn_mfma_f32_16x16x32_bf16(a, b0, accA[ms][0], 0, 0, 0);
                accA[ms][1] = __builtin_amdgcn_mfma_f32_16x16x32_bf16(a, b1, accA[ms][1], 0, 0, 0);
            }
        }
        __builtin_amdgcn_s_setprio(0);
        // ---- epilogue A: fixed-shift sum for comp0; fold u1+cv into accB init ----
        f32x4 accB[4][2];
#pragma unroll
        for (int ns = 0; ns < 2; ns++) {
            int col = n0 + (ns << 4) + ln;
            bool ok = col < VV;
            float bpv = ok ? b_prior[col] : 0.f;
            float cvv = ok ? cv[col] : 0.f;
#pragma unroll
            for (int ms = 0; ms < 4; ms++)
#pragma unroll
                for (int r = 0; r < 4; r++) {
                    int r16 = (ms << 2) + r;
                    float u1 = ok ? accA[ms][ns][r] + bpv : -1e30f;
                    Ls[0][r16] += __expf(u1 - FMSHIFT);  // exp(-1e30)=0 for pads
                    accB[ms][ns][r] = ok ? u1 + cvv : -1e30f;  // pad Qb rows are 0
                }
        }
        __builtin_amdgcn_s_setprio(1);
        // ---- chain B: z (kc 0..7) + z^2 (kc 8..15) vs Qb ----
#pragma unroll 2
        for (int kc = 0; kc < 16; kc++) {
            bf16x8 bq0 = Qb8[rb + (kc << 2) + quad];
            bf16x8 bq1 = Qb8[rb + 1024 + (kc << 2) + quad];
#pragma unroll
            for (int ms = 0; ms < 4; ms++) {
                bf16x8 a = fz8[(kc << 8) + g0 + (ms << 6)];
                accB[ms][0] = __builtin_amdgcn_mfma_f32_16x16x32_bf16(a, bq0, accB[ms][0], 0, 0, 0);
                accB[ms][1] = __builtin_amdgcn_mfma_f32_16x16x32_bf16(a, bq1, accB[ms][1], 0, 0, 0);
            }
        }
        __builtin_amdgcn_s_setprio(0);
        // ---- epilogue B: online LSE (comp1 has unbounded-scale lp) ----
#pragma unroll
        for (int ns = 0; ns < 2; ns++)
#pragma unroll
            for (int ms = 0; ms < 4; ms++)
#pragma unroll
                for (int r = 0; r < 4; r++) {
                    int r16 = (ms << 2) + r;
                    float u2 = accB[ms][ns][r];
                    float nm = fmaxf(Lm1[r16], u2);
                    Ls[1][r16] = Ls[1][r16] * __expf(Lm1[r16] - nm) + __expf(u2 - nm);
                    Lm1[r16] = nm;
                }
        // ---- chain C: gen logits, z (K=256) vs Gb ----
        f32x4 accC[4][2];
#pragma unroll
        for (int ns = 0; ns < 2; ns++) {
            int col = n0 + (ns << 4) + ln;
            bool ok = col < VV;
            float bgv = ok ? b_gen[col] : -1e30f;  // pad Gb rows are 0
#pragma unroll
            for (int ms = 0; ms < 4; ms++) accC[ms][ns] = bgv;
        }
        __builtin_amdgcn_s_setprio(1);
#pragma unroll 2
        for (int kc = 0; kc < 8; kc++) {
            bf16x8 bg0 = Gb8[rg + (kc << 2) + quad];
            bf16x8 bg1 = Gb8[rg + 512 + (kc << 2) + quad];
#pragma unroll
            for (int ms = 0; ms < 4; ms++) {
                bf16x8 a = fz8[(kc << 8) + g0 + (ms << 6)];
                accC[ms][0] = __builtin_amdgcn_mfma_f32_16x16x32_bf16(a, bg0, accC[ms][0], 0, 0, 0);
                accC[ms][1] = __builtin_amdgcn_mfma_f32_16x16x32_bf16(a, bg1, accC[ms][1], 0, 0, 0);
            }
        }
        __builtin_amdgcn_s_setprio(0);
        // ---- epilogue C: fixed-shift sum for comp2 ----
#pragma unroll
        for (int ns = 0; ns < 2; ns++)
#pragma unroll
            for (int ms = 0; ms < 4; ms++)
#pragma unroll
                for (int r = 0; r < 4; r++)
                    Ls[2][(ms << 2) + r] += __expf(accC[ms][ns][r] - FMSHIFT);
    }
    // merge across the 16 col-lanes (same rows; xor of low-4 bits keeps quad)
#pragma unroll
    for (int off = 1; off <= 8; off <<= 1)
#pragma unroll
        for (int r16 = 0; r16 < 16; r16++) {
            Ls[0][r16] += __shfl_xor(Ls[0][r16], off);
            Ls[2][r16] += __shfl_xor(Ls[2][r16], off);
            float mo = __shfl_xor(Lm1[r16], off);
            float so = __shfl_xor(Ls[1][r16], off);
            float nm = fmaxf(Lm1[r16], mo);
            Ls[1][r16] = Ls[1][r16] * __expf(Lm1[r16] - nm) + so * __expf(mo - nm);
            Lm1[r16] = nm;
        }
    // block-level merge across the 8 wave column-slices (staging LDS is dead now)
    __syncthreads();
    float* bs = (float*)sm;   // [3][8 w][64 rows] = 1536
    float* bm = bs + 1536;    // [8 w][64 rows] = 512 (comp1 max only)
    if (ln == 0) {
#pragma unroll
        for (int r16 = 0; r16 < 16; r16++) {
            int row = ((r16 >> 2) << 4) + (quad << 2) + (r16 & 3);
#pragma unroll
            for (int c = 0; c < 3; c++) bs[(c * 8 + w) * 64 + row] = Ls[c][r16];
            bm[w * 64 + row] = Lm1[r16];
        }
    }
    __syncthreads();
    if (tid < 192) {
        int c = tid >> 6, row = tid & 63;
        float M, S;
        if (c == 1) {
            M = -1e30f; S = 0.f;
#pragma unroll
            for (int q = 0; q < 8; q++) {
                float m = bm[q * 64 + row];
                float s = bs[(8 + q) * 64 + row];
                float Mn = fmaxf(M, m);
                S = S * __expf(M - Mn) + s * __expf(m - Mn);
                M = Mn;
            }
        } else {
            M = FMSHIFT; S = 0.f;
#pragma unroll
            for (int q = 0; q < 8; q++) S += bs[(c * 8 + q) * 64 + row];
        }
        part[(vs * 6 + c * 2) * 4096 + bt0 + row] = M;
        part[(vs * 6 + c * 2 + 1) * 4096 + bt0 + row] = S;
    }
}

// ---------------- 8) finalize (merge 8 V-split partials), 2-stage ----------------
__device__ __forceinline__ float lse8(const float* __restrict__ part, int comp, int bt) {
    float M = -1e30f, S = 0.f;
#pragma unroll
    for (int vsi = 0; vsi < 8; vsi++) {
        float m = part[(vsi * 6 + comp) * 4096 + bt];
        float s = part[(vsi * 6 + comp + 1) * 4096 + bt];
        float Mn = fmaxf(M, m);
        S = S * __expf(M - Mn) + s * __expf(m - Mn);
        M = Mn;
    }
    return M + logf(S);
}

// stage 1: 32 blocks x 128 threads — block bid handles batch b = bid (bt = bid*128 + t)
__global__ void k_final1(const float* __restrict__ part, const float* __restrict__ qz,
                         const float* __restrict__ gxv, const int* __restrict__ x_sl,
                         float* __restrict__ psum) {
    int bid = blockIdx.x;
    int tid = threadIdx.x;
    int bt = (bid << 7) + tid;
    float S = 0.f;
    if (tid < x_sl[bid]) {
        float lse1 = lse8(part, 0, bt);
        float lse2 = lse8(part, 2, bt);
        float lse3 = lse8(part, 4, bt);
        float p_z = lse2 - lse1;
        float kl = qz[bt] - p_z;
        float px = gxv[bt] - lse3;
        S = px - kl;
    }
    __shared__ float red[128];
    red[tid] = S;
    __syncthreads();
    for (int s = 64; s > 0; s >>= 1) {
        if (tid < s) red[tid] += red[tid + s];
        __syncthreads();
    }
    if (tid == 0) psum[bid] = red[0];
}

// stage 2: 1 block x 64 threads — reduce 32 partials, divide, negate
__global__ void k_final2(const float* __restrict__ psum, const int* __restrict__ x_sl,
                         float* __restrict__ out) {
    int tid = threadIdx.x;
    float s = (tid < 32) ? psum[tid] : 0.f;
#pragma unroll
    for (int off = 32; off >= 1; off >>= 1) s += __shfl_down(s, off);
    if (tid == 0) {
        int sl = 0;
        for (int b = 0; b < 32; b++) sl += x_sl[b];
        out[0] = -(s / (float)sl);
    }
}

extern "C" void kernel_launch(void* const* d_in, const int* in_sizes, int n_in,
                              void* d_out, int out_size, void* d_ws, size_t ws_size,
                              hipStream_t stream) {
    const int* x = (const int*)d_in[0];
    const int* x_sl = (const int*)d_in[1];
    const float* eps = (const float*)d_in[2];
    const float* emb = (const float*)d_in[3];
    const float* w_ih = (const float*)d_in[4];
    const float* w_hh = (const float*)d_in[5];
    const float* b_ih = (const float*)d_in[6];
    const float* b_hh = (const float*)d_in[7];
    const float* w_prior = (const float*)d_in[8];
    const float* b_prior = (const float*)d_in[9];
    const float* w_gen = (const float*)d_in[10];
    const float* b_gen = (const float*)d_in[11];

    float* ws = (float*)d_ws;
    float* qz = ws + 1048576;
    ushort* hb = (ushort*)(ws + 1052672);            // BT*H bf16 = 4 MB
    ushort* zb = (ushort*)(ws + 1052672 + 1048576);  // BT*K bf16 = 2 MB
    float* gx = ws + 3149824;
    float* region = ws + 3252224;
    float* xp = region;
    uint4* wpIF = (uint4*)(region + 8388608);
    uint4* wpGO = wpIF + 65536;
    unsigned* hpk = (unsigned*)(region + 8912896);  // 1048576 dwords
    ushort* wb = (ushort*)(region + 9961472);       // w_ih bf16, 1 MB (phase 1)
    ushort* Pb = (ushort*)(region);                 // phase 2 (xp dead)
    ushort* Qb = (ushort*)(region + 2621440);
    ushort* Gb = (ushort*)(region + 5242880);
    float* part = region + 6553600;                 // 8*6*4096
    float* psum = region + 6750208;                 // 32 floats
    float* cv = region + 13107200;

    k_embed<<<4096, 256, 0, stream>>>(x, x_sl, eps, emb, w_gen, b_gen, zb, qz, gx);
    k_pack_w<<<512, 256, 0, stream>>>(w_ih, wb, 6);  // w_ih -> bf16 (2048 rows < VV)
    k_xpm<<<512, 512, 0, stream>>>(zb, wb, b_ih, b_hh, xp);
    k_wpack2<<<dim3(256, 2), 256, 0, stream>>>(w_hh, wpIF, wpGO);
    hipMemsetAsync(hpk, 0xFF, 4194304, stream);  // sentinel: f16 NaN pairs
    {
        hipFuncSetAttribute((const void*)k_lstm, hipFuncAttributeMaxDynamicSharedMemorySize, 135424);
        void* args[] = {(void*)&xp, (void*)&wpIF, (void*)&wpGO, (void*)&hb, (void*)&hpk};
        hipLaunchCooperativeKernel((const void*)k_lstm, dim3(128), dim3(256), args, 135424, stream);
    }
    // xp/wpIF/wpGO/hpk/wb dead; overlay Pb/Qb/Gb/part/psum/cv
    k_pack_w<<<5120, 256, 0, stream>>>(w_prior, Pb, 7);
    k_pack_w<<<2560, 256, 0, stream>>>(w_gen, Gb, 6);
    k_pack_q<<<10240, 256, 0, stream>>>(emb, Qb, cv);
    hipFuncSetAttribute((const void*)k_scores, hipFuncAttributeMaxDynamicSharedMemorySize, 131072);
    k_scores<<<512, 512, 131072, stream>>>(hb, zb, Pb, Qb, Gb, cv, b_prior, b_gen, part);
    k_final1<<<32, 128, 0, stream>>>(part, qz, gx, x_sl, psum);
    k_final2<<<1, 64, 0, stream>>>(psum, x_sl, (float*)d_out);
}

// Round 15
// 717.748 us; speedup vs baseline: 1.3110x; 1.3110x over previous
//
#include <hip/hip_runtime.h>
#include <hip/hip_bf16.h>
#include <math.h>

// Sizes fixed by the problem
#define BB 32
#define TT 128
#define KK 256
#define HH 512
#define VV 10000
#define VP 10240
#define BT 4096           // B*T
#define HLOG2PI 0.91893853320467274178f
#define FMSHIFT 16.0f     // fixed LSE shift for bounded-logit comps (|u| <= ~10)

// ---- workspace layout (float offsets) ----
// qz      : 1048576    4096
// hb      : 1052672    BT*H bf16 (ushort)
// zb      : 2101248    BT*K bf16 (ushort)
// gx      : 3149824    4096
// region  : 3252224    13117440
//  phase 1 (lstm): xp(0..8388608) wpIF(+8388608) wpGO(+8650752)
//                  hpk(+8912896, 1048576 dwords) wb(+9961472, 524288 ushorts)
//  phase 2 (scores), overlaying dead xp: Pb / Qb / Gb / part / psum / cv

typedef short bf16x8 __attribute__((ext_vector_type(8)));
typedef float f32x4 __attribute__((ext_vector_type(4)));

__device__ __forceinline__ float softplus_b(float x) {
    float ax = fabsf(x);
    return fmaxf(x, 0.0f) + log2f(1.0f + exp2f(-ax));
}
__device__ __forceinline__ float sigm(float x) { return 1.0f / (1.0f + expf(-x)); }
// fast variants for the LSTM serial gate path (bf16-level accuracy is plenty)
__device__ __forceinline__ float fsigm(float x) { return 1.0f / (1.0f + __expf(-x)); }
__device__ __forceinline__ float ftanh(float x) {
    float e = __expf(2.0f * x);
    return 1.0f - 2.0f / (e + 1.0f);
}
__device__ __forceinline__ unsigned short f2bf(float f) {
    unsigned u = __float_as_uint(f);
    u += 0x7FFFu + ((u >> 16) & 1u);
    return (unsigned short)(u >> 16);
}
typedef _Float16 h2f16 __attribute__((ext_vector_type(2)));
__device__ __forceinline__ unsigned pkh2(float a, float b) {
    h2f16 h;
    h.x = (_Float16)a;
    h.y = (_Float16)b;
    return *(unsigned*)&h;
}
__device__ __forceinline__ float fdot2u(unsigned a, unsigned b, float c) {
    h2f16 ah = *(h2f16*)&a, bh = *(h2f16*)&b;
#if __has_builtin(__builtin_amdgcn_fdot2)
    return __builtin_amdgcn_fdot2(ah, bh, c, false);
#else
    return c + (float)ah.x * (float)bh.x + (float)ah.y * (float)bh.y;
#endif
}
// square a bf16x8 in-register: bf16->f32 is <<16; repack with v_cvt_pk_bf16_f32 (RNE)
__device__ __forceinline__ bf16x8 bsq(bf16x8 a) {
    union { bf16x8 v; unsigned w[4]; } u, r;
    u.v = a;
#pragma unroll
    for (int i = 0; i < 4; i++) {
        float lo = __uint_as_float(u.w[i] << 16);
        float hi = __uint_as_float(u.w[i] & 0xFFFF0000u);
        lo *= lo;
        hi *= hi;
        asm("v_cvt_pk_bf16_f32 %0, %1, %2" : "=v"(r.w[i]) : "v"(lo), "v"(hi));
    }
    return r.v;
}

// ---------------- 1) embedding -> zb (bf16), q_z_lp, gx (fused k_gx) ----------------
__global__ void k_embed(const int* __restrict__ x, const int* __restrict__ x_sl,
                        const float* __restrict__ eps, const float* __restrict__ emb,
                        const float* __restrict__ w_gen, const float* __restrict__ b_gen,
                        ushort* __restrict__ zb, float* __restrict__ qz,
                        float* __restrict__ gx) {
    int bt = blockIdx.x;
    int b = bt >> 7, t = bt & 127;
    int k = threadIdx.x;
    int xi = x[bt];
    float e1 = emb[xi * 512 + k];
    float sg = softplus_b(emb[xi * 512 + 256 + k]);
    float ep = eps[bt * 256 + k];
    float mk = (t < x_sl[b]) ? 1.f : 0.f;
    float zv = (e1 + sg * ep) * mk;
    zb[bt * 256 + k] = f2bf(zv);
    float q = -HLOG2PI - logf(sg) - 0.5f * ep * ep;
    float p = zv * w_gen[xi * 256 + k];  // fused k_gx dot term (f32 z in-register)
    __shared__ float red[256];
    red[k] = q;
    __syncthreads();
    for (int s = 128; s > 0; s >>= 1) {
        if (k < s) red[k] += red[k + s];
        __syncthreads();
    }
    if (k == 0) qz[bt] = red[0];
    __syncthreads();
    red[k] = p;
    __syncthreads();
    for (int s = 128; s > 0; s >>= 1) {
        if (k < s) red[k] += red[k + s];
        __syncthreads();
    }
    if (k == 0) gx[bt] = red[0] + b_gen[xi];
}

// ---------------- 2) x_proj via MFMA: xp = z_shift @ w_ih^T + b_ih + b_hh ----------------
__global__ __launch_bounds__(512) void k_xpm(const ushort* __restrict__ zb,
                                             const ushort* __restrict__ wb,
                                             const float* __restrict__ b_ih,
                                             const float* __restrict__ b_hh,
                                             float* __restrict__ xp) {
    __shared__ ushort zs[16384];  // [kc 8][256 granules of 16B], swizzled
    int tid = threadIdx.x;
    int mb = blockIdx.x >> 3;
    int nb = blockIdx.x & 7;
    int bt0 = mb << 6;
    int n0base = nb << 8;
    // stage A: z_shift rows bt0..bt0+63 (t==0 -> zeros), bf16 16B copies
    for (int i = tid; i < 2048; i += 512) {
        int quad = i & 3, row = (i >> 2) & 63, kc = i >> 8;  // kc 0..7
        int bt = bt0 + row;
        uint4 v = make_uint4(0, 0, 0, 0);
        if ((bt & 127) != 0)
            v = *(const uint4*)(zb + (size_t)(bt - 1) * 256 + kc * 32 + quad * 8);
        int g = (((row << 2) + (quad ^ (row & 3))) ^ (((row >> 2) & 1) << 2));
        *(uint4*)(zs + kc * 2048 + g * 8) = v;
    }
    __syncthreads();
    int w = tid >> 6, l = tid & 63;
    int quad = l >> 4, ln = l & 15;
    int n0 = n0base + (w << 5);
    const bf16x8* zs8 = (const bf16x8*)zs;
    const bf16x8* wb8 = (const bf16x8*)wb;
    int g0 = (((ln << 2) + (quad ^ (ln & 3))) ^ (((ln >> 2) & 1) << 2));
    int rb = (n0 + ln) << 5;  // wb granule row base (32 granules/row; ns adds 512)
    f32x4 acc[4][2];
#pragma unroll
    for (int ns = 0; ns < 2; ns++) {
        int col = n0 + (ns << 4) + ln;
        float bias = b_ih[col] + b_hh[col];
#pragma unroll
        for (int ms = 0; ms < 4; ms++) acc[ms][ns] = bias;
    }
#pragma unroll
    for (int kc = 0; kc < 8; kc++) {
        bf16x8 b0 = wb8[rb + (kc << 2) + quad];
        bf16x8 b1 = wb8[rb + 512 + (kc << 2) + quad];
#pragma unroll
        for (int ms = 0; ms < 4; ms++) {
            bf16x8 a = zs8[(kc << 8) + g0 + (ms << 6)];
            acc[ms][0] = __builtin_amdgcn_mfma_f32_16x16x32_bf16(a, b0, acc[ms][0], 0, 0, 0);
            acc[ms][1] = __builtin_amdgcn_mfma_f32_16x16x32_bf16(a, b1, acc[ms][1], 0, 0, 0);
        }
    }
    // write: row = 16*ms + 4*quad + r, col = n0 + 16*ns + ln
#pragma unroll
    for (int ms = 0; ms < 4; ms++)
#pragma unroll
        for (int ns = 0; ns < 2; ns++)
#pragma unroll
            for (int r = 0; r < 4; r++) {
                int row = bt0 + (ms << 4) + (quad << 2) + r;
                xp[(size_t)row * 2048 + n0 + (ns << 4) + ln] = acc[ms][ns][r];
            }
}

// ---------------- 2b) pack w_hh -> f16 pairs, layouts for k_lstm ----------------
__global__ __launch_bounds__(256) void k_wpack2(const float* __restrict__ w_hh,
                                                uint4* __restrict__ wpIF,
                                                uint4* __restrict__ wpGO) {
    int o = blockIdx.x * 256 + threadIdx.x;  // 0..65535
    if (blockIdx.y == 0) {
        int kq = o & 3, j_local = (o >> 2) & 63, q = (o >> 8) & 31, m = o >> 13;
        int jg = (m << 6) + j_local;
        int k = (kq << 7) + (q << 2);
        const float* wi = w_hh + (size_t)jg * 512 + k;
        const float* wf = w_hh + (size_t)(512 + jg) * 512 + k;
        uint4 u;
        u.x = pkh2(wi[0], wi[1]); u.y = pkh2(wi[2], wi[3]);
        u.z = pkh2(wf[0], wf[1]); u.w = pkh2(wf[2], wf[3]);
        wpIF[o] = u;
    } else {
        int q = o & 31, kq = (o >> 5) & 3, j_local = (o >> 7) & 63, m = o >> 13;
        int jg = (m << 6) + j_local;
        int k = (kq << 7) + (q << 2);
        const float* wg = w_hh + (size_t)(1024 + jg) * 512 + k;
        const float* wo = w_hh + (size_t)(1536 + jg) * 512 + k;
        uint4 u;
        u.x = pkh2(wg[0], wg[1]); u.y = pkh2(wg[2], wg[3]);
        u.z = pkh2(wo[0], wo[1]); u.w = pkh2(wo[2], wo[3]);
        wpGO[o] = u;
    }
}

// ---------------- 3) LSTM v5 (REVERT from v6): proven 272 us version ----------------
// r14 post-mortem: 2-batch/block doubled serialized poll RTTs (4670 cyc/batch-
// step unchanged) -> 498 us. The poll-per-step RTT is structural; v5 (272 us,
// skewed conflict-free exchange, 256 blocks) is the verified local optimum.
__global__ __launch_bounds__(256, 1) void k_lstm(const float* __restrict__ xp,
                                                 const uint4* __restrict__ wpIF,
                                                 const uint4* __restrict__ wpGO,
                                                 ushort* __restrict__ h_all,
                                                 unsigned* __restrict__ hpk) {
    extern __shared__ char smc[];
    uint4* wif = (uint4*)smc;                   // [q 32][wave-linear 256] = 128 KB
    unsigned* hs2 = (unsigned*)(smc + 131072);  // [2][272] dwords (skewed)
    int bid = blockIdx.x;
    int b = bid & 31;
    int m = bid >> 5;
    int tid = threadIdx.x;
    int w = tid >> 6, l = tid & 63;
    int jj = l >> 2, kq = l & 3;
    int j_local = (w << 4) + jj;
    int j_global = (m << 6) + j_local;
    const uint4* srcIF = wpIF + ((size_t)m << 13);
    for (int i = tid; i < 8192; i += 256) wif[i] = srcIF[i];
    uint4 wgo[32];
    const uint4* srcGO = wpGO + ((size_t)((((m << 6) + j_local) << 2) + kq) << 5);
#pragma unroll
    for (int q = 0; q < 32; q++) wgo[q] = srcGO[q];
    const uint4* wifp = wif + (w << 6) + l;
    int skslot = tid + ((tid >> 6) << 2);  // skewed write slot
    float c = 0.f;
    __syncthreads();
    for (int t = 0; t < 128; t++) {
        int bt = (b << 7) + t;
        float xg0 = 0.f, xg1 = 0.f, xg2 = 0.f, xg3 = 0.f;
        if (kq == 0) {  // prefetch xp before the poll (independent loads)
            const float* xpr = xp + (size_t)bt * 2048 + j_global;
            xg0 = xpr[0]; xg1 = xpr[512]; xg2 = xpr[1024]; xg3 = xpr[1536];
        }
        float a0 = 0.f, a1 = 0.f, a2 = 0.f, a3 = 0.f;
        if (t > 0) {
            const unsigned* src = hpk + ((size_t)(bt - 1) << 8);
            unsigned u;
            do {
                u = __hip_atomic_load(src + tid, __ATOMIC_RELAXED, __HIP_MEMORY_SCOPE_AGENT);
            } while (u == 0xFFFFFFFFu);
            unsigned* hbuf = hs2 + ((t - 1) & 1) * 272;
            hbuf[skslot] = u;
            __syncthreads();
            const unsigned* hp2 = hbuf + kq * 68;
#pragma unroll
            for (int q = 0; q < 32; q++) {
                uint4 A = wifp[q << 8];
                uint4 B = wgo[q];
                unsigned p0 = hp2[q << 1];
                unsigned p1 = hp2[(q << 1) + 1];
                a0 = fdot2u(A.x, p0, a0); a0 = fdot2u(A.y, p1, a0);
                a1 = fdot2u(A.z, p0, a1); a1 = fdot2u(A.w, p1, a1);
                a2 = fdot2u(B.x, p0, a2); a2 = fdot2u(B.y, p1, a2);
                a3 = fdot2u(B.z, p0, a3); a3 = fdot2u(B.w, p1, a3);
            }
#pragma unroll
            for (int off = 1; off <= 2; off <<= 1) {
                a0 += __shfl_xor(a0, off);
                a1 += __shfl_xor(a1, off);
                a2 += __shfl_xor(a2, off);
                a3 += __shfl_xor(a3, off);
            }
        }
        float h = 0.f;
        if (kq == 0) {
            float g0 = xg0 + a0, g1 = xg1 + a1, g2 = xg2 + a2, g3 = xg3 + a3;
            c = fsigm(g1) * c + fsigm(g0) * ftanh(g2);
            h = fsigm(g3) * ftanh(c);
            h_all[(size_t)bt * 512 + j_global] = f2bf(h);  // bf16, read post-kernel
        }
        float hp = __shfl_xor(h, 4);  // leader jj even <- h of jj+1
        if (kq == 0 && (jj & 1) == 0) {
            unsigned u = pkh2(h, hp);
            __hip_atomic_store(hpk + ((size_t)bt << 8) + (m << 5) + (w << 3) + (jj >> 1),
                               u, __ATOMIC_RELAXED, __HIP_MEMORY_SCOPE_AGENT);
        }
    }
}

// ---------------- 4a) cast weights -> bf16 row-major [v][2^kshift granules] ----------------
__global__ __launch_bounds__(256) void k_pack_w(const float* __restrict__ src,
                                                ushort* __restrict__ dst, int kshift) {
    int o = blockIdx.x * 256 + threadIdx.x;  // one ushort4 unit
    int c = o & ((1 << kshift) - 1);
    int r = o >> kshift;
    ushort4 u = make_ushort4(0, 0, 0, 0);
    if (r < VV) {
        float4 v = *(const float4*)(src + ((size_t)r << (kshift + 2)) + (c << 2));
        u = make_ushort4(f2bf(v.x), f2bf(v.y), f2bf(v.z), f2bf(v.w));
    }
    *(ushort4*)(dst + ((size_t)o << 2)) = u;
}

// ---------------- 4b) Qb rows [2*iv*mu (256) | -iv (256)] bf16 + const_v ----------------
__global__ void k_pack_q(const float* __restrict__ emb, ushort* __restrict__ Qb,
                         float* __restrict__ cv) {
    int v = blockIdx.x, k = threadIdx.x;
    if (v >= VV) {
        Qb[((size_t)v << 9) + k] = 0;
        Qb[((size_t)v << 9) + 256 + k] = 0;
        if (k == 0) cv[v] = 0.f;
        return;
    }
    float mu = emb[(size_t)v * 512 + k];
    float sg = softplus_b(emb[(size_t)v * 512 + 256 + k]);
    float iv = 0.5f / (sg * sg);
    Qb[((size_t)v << 9) + k] = f2bf(2.f * iv * mu);
    Qb[((size_t)v << 9) + 256 + k] = f2bf(-iv);
    float ct = -HLOG2PI - logf(sg) - mu * mu * iv;
    __shared__ float red[256];
    red[k] = ct;
    __syncthreads();
    for (int s = 128; s > 0; s >>= 1) {
        if (k < s) red[k] += red[k + s];
        __syncthreads();
    }
    if (k == 0) cv[v] = red[0];
}

// ---------------- 6) fused scores v7: fixed-shift LSE for bounded comps ----------------
__global__ __launch_bounds__(512, 2) void k_scores(
    const ushort* __restrict__ hb, const ushort* __restrict__ zb,
    const ushort* __restrict__ Pb, const ushort* __restrict__ Qb,
    const ushort* __restrict__ Gb, const float* __restrict__ cv,
    const float* __restrict__ b_prior, const float* __restrict__ b_gen,
    float* __restrict__ part) {
    extern __shared__ ushort sm[];
    ushort* hT = sm;           // [kc 16][64 rows][32], swizzled granules = 64 KB
    ushort* fzT = sm + 32768;  // [kc 16][64 rows][32]: kc<8 z, kc>=8 z^2 = 64 KB
    int tid = threadIdx.x;
    int vs = blockIdx.x & 7;
    int mb = blockIdx.x >> 3;
    int bt0 = mb << 6;
    int vbase = vs * 1280;
    // stage h tile (64 x 512 bf16): pure 16B copies
    for (int i = tid; i < 4096; i += 512) {
        int quad = i & 3, row = (i >> 2) & 63, kc = i >> 8;
        uint4 v = *(const uint4*)(hb + (size_t)(bt0 + row) * 512 + kc * 32 + quad * 8);
        int g = (((row << 2) + (quad ^ (row & 3))) ^ (((row >> 2) & 1) << 2));
        *(uint4*)(hT + kc * 2048 + g * 8) = v;
    }
    // stage z (copy) + z^2 (bsq once per granule)
    for (int i = tid; i < 2048; i += 512) {
        int quad = i & 3, row = (i >> 2) & 63, kc = i >> 8;  // kc 0..7
        uint4 v = *(const uint4*)(zb + (size_t)(bt0 + row) * 256 + kc * 32 + quad * 8);
        int g = (((row << 2) + (quad ^ (row & 3))) ^ (((row >> 2) & 1) << 2));
        *(uint4*)(fzT + kc * 2048 + g * 8) = v;
        bf16x8 sq = bsq(*(bf16x8*)&v);
        *(uint4*)(fzT + (kc + 8) * 2048 + g * 8) = *(uint4*)&sq;
    }
    __syncthreads();
    int w = tid >> 6, l = tid & 63;
    int quad = l >> 4, ln = l & 15;
    int nq = w;  // wave: ALL 64 rows x cols nq*32..+32 per nt group
    const bf16x8* hT8 = (const bf16x8*)hT;
    const bf16x8* fz8 = (const bf16x8*)fzT;
    const bf16x8* Pb8 = (const bf16x8*)Pb;
    const bf16x8* Qb8 = (const bf16x8*)Qb;
    const bf16x8* Gb8 = (const bf16x8*)Gb;
    // ms=0 row = ln; ms adds 16 rows => granule g0 + 64*ms (swizzle-consistent)
    int g0 = (((ln << 2) + (quad ^ (ln & 3))) ^ (((ln >> 2) & 1) << 2));
    float Ls[3][16], Lm1[16];
#pragma unroll
    for (int c = 0; c < 3; c++)
#pragma unroll
        for (int r = 0; r < 16; r++) Ls[c][r] = 0.f;
#pragma unroll
    for (int r = 0; r < 16; r++) Lm1[r] = -1e30f;
#pragma unroll 1
    for (int nt = 0; nt < 5; nt++) {
        int n0 = vbase + (nt << 8) + (nq << 5);
        int rb = (n0 + ln) << 6;  // Pb/Qb granule row base (ns adds 1024)
        int rg = (n0 + ln) << 5;  // Gb granule row base (ns adds 512)
        __builtin_amdgcn_s_setprio(1);
        // ---- chain A: prior logits, h (K=512) vs Pb ----
        f32x4 accA[4][2];
#pragma unroll
        for (int ms = 0; ms < 4; ms++) { accA[ms][0] = 0.f; accA[ms][1] = 0.f; }
#pragma unroll 2
        for (int kc = 0; kc < 16; kc++) {
            bf16x8 b0 = Pb8[rb + (kc << 2) + quad];
            bf16x8 b1 = Pb8[rb + 1024 + (kc << 2) + quad];
#pragma unroll
            for (int ms = 0; ms < 4; ms++) {
                bf16x8 a = hT8[(kc << 8) + g0 + (ms << 6)];
                accA[ms][0] = __builtin_amdgcn_mfma_f32_16x16x32_bf16(a, b0, accA[ms][0], 0, 0, 0);
                accA[ms][1] = __builtin_amdgcn_mfma_f32_16x16x32_bf16(a, b1, accA[ms][1], 0, 0, 0);
            }
        }
        __builtin_amdgcn_s_setprio(0);
        // ---- epilogue A: fixed-shift sum for comp0; fold u1+cv into accB init ----
        f32x4 accB[4][2];
#pragma unroll
        for (int ns = 0; ns < 2; ns++) {
            int col = n0 + (ns << 4) + ln;
            bool ok = col < VV;
            float bpv = ok ? b_prior[col] : 0.f;
            float cvv = ok ? cv[col] : 0.f;
#pragma unroll
            for (int ms = 0; ms < 4; ms++)
#pragma unroll
                for (int r = 0; r < 4; r++) {
                    int r16 = (ms << 2) + r;
                    float u1 = ok ? accA[ms][ns][r] + bpv : -1e30f;
                    Ls[0][r16] += __expf(u1 - FMSHIFT);  // exp(-1e30)=0 for pads
                    accB[ms][ns][r] = ok ? u1 + cvv : -1e30f;  // pad Qb rows are 0
                }
        }
        __builtin_amdgcn_s_setprio(1);
        // ---- chain B: z (kc 0..7) + z^2 (kc 8..15) vs Qb ----
#pragma unroll 2
        for (int kc = 0; kc < 16; kc++) {
            bf16x8 bq0 = Qb8[rb + (kc << 2) + quad];
            bf16x8 bq1 = Qb8[rb + 1024 + (kc << 2) + quad];
#pragma unroll
            for (int ms = 0; ms < 4; ms++) {
                bf16x8 a = fz8[(kc << 8) + g0 + (ms << 6)];
                accB[ms][0] = __builtin_amdgcn_mfma_f32_16x16x32_bf16(a, bq0, accB[ms][0], 0, 0, 0);
                accB[ms][1] = __builtin_amdgcn_mfma_f32_16x16x32_bf16(a, bq1, accB[ms][1], 0, 0, 0);
            }
        }
        __builtin_amdgcn_s_setprio(0);
        // ---- epilogue B: online LSE (comp1 has unbounded-scale lp) ----
#pragma unroll
        for (int ns = 0; ns < 2; ns++)
#pragma unroll
            for (int ms = 0; ms < 4; ms++)
#pragma unroll
                for (int r = 0; r < 4; r++) {
                    int r16 = (ms << 2) + r;
                    float u2 = accB[ms][ns][r];
                    float nm = fmaxf(Lm1[r16], u2);
                    Ls[1][r16] = Ls[1][r16] * __expf(Lm1[r16] - nm) + __expf(u2 - nm);
                    Lm1[r16] = nm;
                }
        // ---- chain C: gen logits, z (K=256) vs Gb ----
        f32x4 accC[4][2];
#pragma unroll
        for (int ns = 0; ns < 2; ns++) {
            int col = n0 + (ns << 4) + ln;
            bool ok = col < VV;
            float bgv = ok ? b_gen[col] : -1e30f;  // pad Gb rows are 0
#pragma unroll
            for (int ms = 0; ms < 4; ms++) accC[ms][ns] = bgv;
        }
        __builtin_amdgcn_s_setprio(1);
#pragma unroll 2
        for (int kc = 0; kc < 8; kc++) {
            bf16x8 bg0 = Gb8[rg + (kc << 2) + quad];
            bf16x8 bg1 = Gb8[rg + 512 + (kc << 2) + quad];
#pragma unroll
            for (int ms = 0; ms < 4; ms++) {
                bf16x8 a = fz8[(kc << 8) + g0 + (ms << 6)];
                accC[ms][0] = __builtin_amdgcn_mfma_f32_16x16x32_bf16(a, bg0, accC[ms][0], 0, 0, 0);
                accC[ms][1] = __builtin_amdgcn_mfma_f32_16x16x32_bf16(a, bg1, accC[ms][1], 0, 0, 0);
            }
        }
        __builtin_amdgcn_s_setprio(0);
        // ---- epilogue C: fixed-shift sum for comp2 ----
#pragma unroll
        for (int ns = 0; ns < 2; ns++)
#pragma unroll
            for (int ms = 0; ms < 4; ms++)
#pragma unroll
                for (int r = 0; r < 4; r++)
                    Ls[2][(ms << 2) + r] += __expf(accC[ms][ns][r] - FMSHIFT);
    }
    // merge across the 16 col-lanes (same rows; xor of low-4 bits keeps quad)
#pragma unroll
    for (int off = 1; off <= 8; off <<= 1)
#pragma unroll
        for (int r16 = 0; r16 < 16; r16++) {
            Ls[0][r16] += __shfl_xor(Ls[0][r16], off);
            Ls[2][r16] += __shfl_xor(Ls[2][r16], off);
            float mo = __shfl_xor(Lm1[r16], off);
            float so = __shfl_xor(Ls[1][r16], off);
            float nm = fmaxf(Lm1[r16], mo);
            Ls[1][r16] = Ls[1][r16] * __expf(Lm1[r16] - nm) + so * __expf(mo - nm);
            Lm1[r16] = nm;
        }
    // block-level merge across the 8 wave column-slices (staging LDS is dead now)
    __syncthreads();
    float* bs = (float*)sm;   // [3][8 w][64 rows] = 1536
    float* bm = bs + 1536;    // [8 w][64 rows] = 512 (comp1 max only)
    if (ln == 0) {
#pragma unroll
        for (int r16 = 0; r16 < 16; r16++) {
            int row = ((r16 >> 2) << 4) + (quad << 2) + (r16 & 3);
#pragma unroll
            for (int c = 0; c < 3; c++) bs[(c * 8 + w) * 64 + row] = Ls[c][r16];
            bm[w * 64 + row] = Lm1[r16];
        }
    }
    __syncthreads();
    if (tid < 192) {
        int c = tid >> 6, row = tid & 63;
        float M, S;
        if (c == 1) {
            M = -1e30f; S = 0.f;
#pragma unroll
            for (int q = 0; q < 8; q++) {
                float m = bm[q * 64 + row];
                float s = bs[(8 + q) * 64 + row];
                float Mn = fmaxf(M, m);
                S = S * __expf(M - Mn) + s * __expf(m - Mn);
                M = Mn;
            }
        } else {
            M = FMSHIFT; S = 0.f;
#pragma unroll
            for (int q = 0; q < 8; q++) S += bs[(c * 8 + q) * 64 + row];
        }
        part[(vs * 6 + c * 2) * 4096 + bt0 + row] = M;
        part[(vs * 6 + c * 2 + 1) * 4096 + bt0 + row] = S;
    }
}

// ---------------- 8) finalize (merge 8 V-split partials), 2-stage ----------------
__device__ __forceinline__ float lse8(const float* __restrict__ part, int comp, int bt) {
    float M = -1e30f, S = 0.f;
#pragma unroll
    for (int vsi = 0; vsi < 8; vsi++) {
        float m = part[(vsi * 6 + comp) * 4096 + bt];
        float s = part[(vsi * 6 + comp + 1) * 4096 + bt];
        float Mn = fmaxf(M, m);
        S = S * __expf(M - Mn) + s * __expf(m - Mn);
        M = Mn;
    }
    return M + logf(S);
}

// stage 1: 32 blocks x 128 threads — block bid handles batch b = bid (bt = bid*128 + t)
__global__ void k_final1(const float* __restrict__ part, const float* __restrict__ qz,
                         const float* __restrict__ gxv, const int* __restrict__ x_sl,
                         float* __restrict__ psum) {
    int bid = blockIdx.x;
    int tid = threadIdx.x;
    int bt = (bid << 7) + tid;
    float S = 0.f;
    if (tid < x_sl[bid]) {
        float lse1 = lse8(part, 0, bt);
        float lse2 = lse8(part, 2, bt);
        float lse3 = lse8(part, 4, bt);
        float p_z = lse2 - lse1;
        float kl = qz[bt] - p_z;
        float px = gxv[bt] - lse3;
        S = px - kl;
    }
    __shared__ float red[128];
    red[tid] = S;
    __syncthreads();
    for (int s = 64; s > 0; s >>= 1) {
        if (tid < s) red[tid] += red[tid + s];
        __syncthreads();
    }
    if (tid == 0) psum[bid] = red[0];
}

// stage 2: 1 block x 64 threads — reduce 32 partials, divide, negate
__global__ void k_final2(const float* __restrict__ psum, const int* __restrict__ x_sl,
                         float* __restrict__ out) {
    int tid = threadIdx.x;
    float s = (tid < 32) ? psum[tid] : 0.f;
#pragma unroll
    for (int off = 32; off >= 1; off >>= 1) s += __shfl_down(s, off);
    if (tid == 0) {
        int sl = 0;
        for (int b = 0; b < 32; b++) sl += x_sl[b];
        out[0] = -(s / (float)sl);
    }
}

extern "C" void kernel_launch(void* const* d_in, const int* in_sizes, int n_in,
                              void* d_out, int out_size, void* d_ws, size_t ws_size,
                              hipStream_t stream) {
    const int* x = (const int*)d_in[0];
    const int* x_sl = (const int*)d_in[1];
    const float* eps = (const float*)d_in[2];
    const float* emb = (const float*)d_in[3];
    const float* w_ih = (const float*)d_in[4];
    const float* w_hh = (const float*)d_in[5];
    const float* b_ih = (const float*)d_in[6];
    const float* b_hh = (const float*)d_in[7];
    const float* w_prior = (const float*)d_in[8];
    const float* b_prior = (const float*)d_in[9];
    const float* w_gen = (const float*)d_in[10];
    const float* b_gen = (const float*)d_in[11];

    float* ws = (float*)d_ws;
    float* qz = ws + 1048576;
    ushort* hb = (ushort*)(ws + 1052672);            // BT*H bf16 = 4 MB
    ushort* zb = (ushort*)(ws + 1052672 + 1048576);  // BT*K bf16 = 2 MB
    float* gx = ws + 3149824;
    float* region = ws + 3252224;
    float* xp = region;
    uint4* wpIF = (uint4*)(region + 8388608);
    uint4* wpGO = wpIF + 65536;
    unsigned* hpk = (unsigned*)(region + 8912896);  // 1048576 dwords
    ushort* wb = (ushort*)(region + 9961472);       // w_ih bf16, 1 MB (phase 1)
    ushort* Pb = (ushort*)(region);                 // phase 2 (xp dead)
    ushort* Qb = (ushort*)(region + 2621440);
    ushort* Gb = (ushort*)(region + 5242880);
    float* part = region + 6553600;                 // 8*6*4096
    float* psum = region + 6750208;                 // 32 floats
    float* cv = region + 13107200;

    k_embed<<<4096, 256, 0, stream>>>(x, x_sl, eps, emb, w_gen, b_gen, zb, qz, gx);
    k_pack_w<<<512, 256, 0, stream>>>(w_ih, wb, 6);  // w_ih -> bf16 (2048 rows < VV)
    k_xpm<<<512, 512, 0, stream>>>(zb, wb, b_ih, b_hh, xp);
    k_wpack2<<<dim3(256, 2), 256, 0, stream>>>(w_hh, wpIF, wpGO);
    hipMemsetAsync(hpk, 0xFF, 4194304, stream);  // sentinel: f16 NaN pairs
    {
        hipFuncSetAttribute((const void*)k_lstm, hipFuncAttributeMaxDynamicSharedMemorySize, 133248);
        void* args[] = {(void*)&xp, (void*)&wpIF, (void*)&wpGO, (void*)&hb, (void*)&hpk};
        hipLaunchCooperativeKernel((const void*)k_lstm, dim3(256), dim3(256), args, 133248, stream);
    }
    // xp/wpIF/wpGO/hpk/wb dead; overlay Pb/Qb/Gb/part/psum/cv
    k_pack_w<<<5120, 256, 0, stream>>>(w_prior, Pb, 7);
    k_pack_w<<<2560, 256, 0, stream>>>(w_gen, Gb, 6);
    k_pack_q<<<10240, 256, 0, stream>>>(emb, Qb, cv);
    hipFuncSetAttribute((const void*)k_scores, hipFuncAttributeMaxDynamicSharedMemorySize, 131072);
    k_scores<<<512, 512, 131072, stream>>>(hb, zb, Pb, Qb, Gb, cv, b_prior, b_gen, part);
    k_final1<<<32, 128, 0, stream>>>(part, qz, gx, x_sl, psum);
    k_final2<<<1, 64, 0, stream>>>(psum, x_sl, (float*)d_out);
}

// Round 16
// 676.362 us; speedup vs baseline: 1.3913x; 1.0612x over previous
//
#include <hip/hip_runtime.h>
#include <hip/hip_bf16.h>
#include <math.h>

// Sizes fixed by the problem
#define BB 32
#define TT 128
#define KK 256
#define HH 512
#define VV 10000
#define VP 10240
#define BT 4096           // B*T
#define HLOG2PI 0.91893853320467274178f
#define FMSHIFT 16.0f     // fixed LSE shift for bounded-logit comps (|u| <= ~10)

// ---- workspace layout (float offsets) ----
// qz      : 1048576    4096
// hb      : 1052672    BT*H bf16 (ushort)
// zb      : 2101248    BT*K bf16 (ushort)
// gx      : 3149824    4096
// region  : 3252224    13117440 floats — NO overlay (xp is bf16 now):
//   xpb  = region + 0         4194304  (BT*2048 bf16)
//   wpIF = region + 4194304   262144
//   wpGO = region + 4456448   262144
//   hpk  = region + 4718592   1048576 dwords
//   wb   = region + 5767168   262144  (w_ih bf16)
//   Pb   = region + 6029312   2621440 (10240*512 bf16)
//   Qb   = region + 8650752   2621440
//   Gb   = region + 11272192  1310720
//   part = region + 12582912  196608
//   psum = region + 12779520  32
//   cv   = region + 12779552  10240
// end 12789792 < 13117440 ✓

typedef short bf16x8 __attribute__((ext_vector_type(8)));
typedef float f32x4 __attribute__((ext_vector_type(4)));

__device__ __forceinline__ float softplus_b(float x) {
    float ax = fabsf(x);
    return fmaxf(x, 0.0f) + log2f(1.0f + exp2f(-ax));
}
__device__ __forceinline__ float fsigm(float x) { return 1.0f / (1.0f + __expf(-x)); }
__device__ __forceinline__ float ftanh(float x) {
    float e = __expf(2.0f * x);
    return 1.0f - 2.0f / (e + 1.0f);
}
__device__ __forceinline__ unsigned short f2bf(float f) {
    unsigned u = __float_as_uint(f);
    u += 0x7FFFu + ((u >> 16) & 1u);
    return (unsigned short)(u >> 16);
}
__device__ __forceinline__ float bf2f(unsigned short u) {
    return __uint_as_float(((unsigned)u) << 16);
}
typedef _Float16 h2f16 __attribute__((ext_vector_type(2)));
__device__ __forceinline__ unsigned pkh2(float a, float b) {
    h2f16 h;
    h.x = (_Float16)a;
    h.y = (_Float16)b;
    return *(unsigned*)&h;
}
__device__ __forceinline__ float fdot2u(unsigned a, unsigned b, float c) {
    h2f16 ah = *(h2f16*)&a, bh = *(h2f16*)&b;
#if __has_builtin(__builtin_amdgcn_fdot2)
    return __builtin_amdgcn_fdot2(ah, bh, c, false);
#else
    return c + (float)ah.x * (float)bh.x + (float)ah.y * (float)bh.y;
#endif
}
// square a bf16x8 in-register: bf16->f32 is <<16; repack with v_cvt_pk_bf16_f32 (RNE)
__device__ __forceinline__ bf16x8 bsq(bf16x8 a) {
    union { bf16x8 v; unsigned w[4]; } u, r;
    u.v = a;
#pragma unroll
    for (int i = 0; i < 4; i++) {
        float lo = __uint_as_float(u.w[i] << 16);
        float hi = __uint_as_float(u.w[i] & 0xFFFF0000u);
        lo *= lo;
        hi *= hi;
        asm("v_cvt_pk_bf16_f32 %0, %1, %2" : "=v"(r.w[i]) : "v"(lo), "v"(hi));
    }
    return r.v;
}

// ---------------- 1) embedding -> zb (bf16), q_z_lp, gx (fused k_gx) ----------------
__global__ void k_embed(const int* __restrict__ x, const int* __restrict__ x_sl,
                        const float* __restrict__ eps, const float* __restrict__ emb,
                        const float* __restrict__ w_gen, const float* __restrict__ b_gen,
                        ushort* __restrict__ zb, float* __restrict__ qz,
                        float* __restrict__ gx) {
    int bt = blockIdx.x;
    int b = bt >> 7, t = bt & 127;
    int k = threadIdx.x;
    int xi = x[bt];
    float e1 = emb[xi * 512 + k];
    float sg = softplus_b(emb[xi * 512 + 256 + k]);
    float ep = eps[bt * 256 + k];
    float mk = (t < x_sl[b]) ? 1.f : 0.f;
    float zv = (e1 + sg * ep) * mk;
    zb[bt * 256 + k] = f2bf(zv);
    float q = -HLOG2PI - logf(sg) - 0.5f * ep * ep;
    float p = zv * w_gen[xi * 256 + k];  // fused k_gx dot term (f32 z in-register)
    __shared__ float red[256];
    red[k] = q;
    __syncthreads();
    for (int s = 128; s > 0; s >>= 1) {
        if (k < s) red[k] += red[k + s];
        __syncthreads();
    }
    if (k == 0) qz[bt] = red[0];
    __syncthreads();
    red[k] = p;
    __syncthreads();
    for (int s = 128; s > 0; s >>= 1) {
        if (k < s) red[k] += red[k + s];
        __syncthreads();
    }
    if (k == 0) gx[bt] = red[0] + b_gen[xi];
}

// ---------------- 2) x_proj via MFMA -> bf16 xpb ----------------
__global__ __launch_bounds__(512) void k_xpm(const ushort* __restrict__ zb,
                                             const ushort* __restrict__ wb,
                                             const float* __restrict__ b_ih,
                                             const float* __restrict__ b_hh,
                                             ushort* __restrict__ xpb) {
    __shared__ ushort zs[16384];  // [kc 8][256 granules of 16B], swizzled
    int tid = threadIdx.x;
    int mb = blockIdx.x >> 3;
    int nb = blockIdx.x & 7;
    int bt0 = mb << 6;
    int n0base = nb << 8;
    // stage A: z_shift rows bt0..bt0+63 (t==0 -> zeros), bf16 16B copies
    for (int i = tid; i < 2048; i += 512) {
        int quad = i & 3, row = (i >> 2) & 63, kc = i >> 8;  // kc 0..7
        int bt = bt0 + row;
        uint4 v = make_uint4(0, 0, 0, 0);
        if ((bt & 127) != 0)
            v = *(const uint4*)(zb + (size_t)(bt - 1) * 256 + kc * 32 + quad * 8);
        int g = (((row << 2) + (quad ^ (row & 3))) ^ (((row >> 2) & 1) << 2));
        *(uint4*)(zs + kc * 2048 + g * 8) = v;
    }
    __syncthreads();
    int w = tid >> 6, l = tid & 63;
    int quad = l >> 4, ln = l & 15;
    int n0 = n0base + (w << 5);
    const bf16x8* zs8 = (const bf16x8*)zs;
    const bf16x8* wb8 = (const bf16x8*)wb;
    int g0 = (((ln << 2) + (quad ^ (ln & 3))) ^ (((ln >> 2) & 1) << 2));
    int rb = (n0 + ln) << 5;  // wb granule row base (32 granules/row; ns adds 512)
    f32x4 acc[4][2];
#pragma unroll
    for (int ns = 0; ns < 2; ns++) {
        int col = n0 + (ns << 4) + ln;
        float bias = b_ih[col] + b_hh[col];
#pragma unroll
        for (int ms = 0; ms < 4; ms++) acc[ms][ns] = bias;
    }
#pragma unroll
    for (int kc = 0; kc < 8; kc++) {
        bf16x8 b0 = wb8[rb + (kc << 2) + quad];
        bf16x8 b1 = wb8[rb + 512 + (kc << 2) + quad];
#pragma unroll
        for (int ms = 0; ms < 4; ms++) {
            bf16x8 a = zs8[(kc << 8) + g0 + (ms << 6)];
            acc[ms][0] = __builtin_amdgcn_mfma_f32_16x16x32_bf16(a, b0, acc[ms][0], 0, 0, 0);
            acc[ms][1] = __builtin_amdgcn_mfma_f32_16x16x32_bf16(a, b1, acc[ms][1], 0, 0, 0);
        }
    }
    // write bf16: row = 16*ms + 4*quad + r, col = n0 + 16*ns + ln
#pragma unroll
    for (int ms = 0; ms < 4; ms++)
#pragma unroll
        for (int ns = 0; ns < 2; ns++)
#pragma unroll
            for (int r = 0; r < 4; r++) {
                int row = bt0 + (ms << 4) + (quad << 2) + r;
                xpb[(size_t)row * 2048 + n0 + (ns << 4) + ln] = f2bf(acc[ms][ns][r]);
            }
}

// ---------------- 2b) pack w_hh -> f16 pairs, layouts for k_lstm ----------------
__global__ __launch_bounds__(256) void k_wpack2(const float* __restrict__ w_hh,
                                                uint4* __restrict__ wpIF,
                                                uint4* __restrict__ wpGO) {
    int o = blockIdx.x * 256 + threadIdx.x;  // 0..65535
    if (blockIdx.y == 0) {
        int kq = o & 3, j_local = (o >> 2) & 63, q = (o >> 8) & 31, m = o >> 13;
        int jg = (m << 6) + j_local;
        int k = (kq << 7) + (q << 2);
        const float* wi = w_hh + (size_t)jg * 512 + k;
        const float* wf = w_hh + (size_t)(512 + jg) * 512 + k;
        uint4 u;
        u.x = pkh2(wi[0], wi[1]); u.y = pkh2(wi[2], wi[3]);
        u.z = pkh2(wf[0], wf[1]); u.w = pkh2(wf[2], wf[3]);
        wpIF[o] = u;
    } else {
        int q = o & 31, kq = (o >> 5) & 3, j_local = (o >> 7) & 63, m = o >> 13;
        int jg = (m << 6) + j_local;
        int k = (kq << 7) + (q << 2);
        const float* wg = w_hh + (size_t)(1024 + jg) * 512 + k;
        const float* wo = w_hh + (size_t)(1536 + jg) * 512 + k;
        uint4 u;
        u.x = pkh2(wg[0], wg[1]); u.y = pkh2(wg[2], wg[3]);
        u.z = pkh2(wo[0], wo[1]); u.w = pkh2(wo[2], wo[3]);
        wpGO[o] = u;
    }
}

// ---------------- 3) LSTM v7: v5 LSTM (tid<256, byte-identical) + pack waves ----------------
// 512 threads: waves 0-3 run the proven 272-us LSTM; waves 4-7 build Pb/Gb/Qb/cv
// (40 v-rows/block) in small chunks between the SAME 128 barriers (1 post-staging
// + 127 in-loop). Chunks (<1 us) hide under the ~5100-cyc poll-bound steps.
// Enabled by bf16 xpb: phase-1 + phase-2 buffers now coexist (no overlay).
__global__ __launch_bounds__(512, 1) void k_lstm(
    const ushort* __restrict__ xpb, const uint4* __restrict__ wpIF,
    const uint4* __restrict__ wpGO, ushort* __restrict__ h_all,
    unsigned* __restrict__ hpk,
    const float* __restrict__ w_prior, const float* __restrict__ w_gen2,
    const float* __restrict__ emb,
    ushort* __restrict__ Pb, ushort* __restrict__ Qb, ushort* __restrict__ Gb,
    float* __restrict__ cv) {
    extern __shared__ char smc[];
    uint4* wif = (uint4*)smc;                   // [q 32][wave-linear 256] = 128 KB
    unsigned* hs2 = (unsigned*)(smc + 131072);  // [2][272] dwords (skewed)
    int bid = blockIdx.x;
    int tid = threadIdx.x;
    const uint4* srcIF = wpIF + ((size_t)(bid >> 5) << 13);
    for (int i = tid; i < 8192; i += 512) wif[i] = srcIF[i];
    if (tid < 256) {
        // ================= LSTM path (byte-identical to v5) =================
        int b = bid & 31;
        int m = bid >> 5;
        int w = tid >> 6, l = tid & 63;
        int jj = l >> 2, kq = l & 3;
        int j_local = (w << 4) + jj;
        int j_global = (m << 6) + j_local;
        uint4 wgo[32];
        const uint4* srcGO = wpGO + ((size_t)((((m << 6) + j_local) << 2) + kq) << 5);
#pragma unroll
        for (int q = 0; q < 32; q++) wgo[q] = srcGO[q];
        const uint4* wifp = wif + (w << 6) + l;
        int skslot = tid + ((tid >> 6) << 2);  // skewed write slot
        float c = 0.f;
        __syncthreads();  // barrier #1
        for (int t = 0; t < 128; t++) {
            int bt = (b << 7) + t;
            float xg0 = 0.f, xg1 = 0.f, xg2 = 0.f, xg3 = 0.f;
            if (kq == 0) {  // prefetch xp before the poll (independent loads)
                const ushort* xpr = xpb + (size_t)bt * 2048 + j_global;
                xg0 = bf2f(xpr[0]); xg1 = bf2f(xpr[512]);
                xg2 = bf2f(xpr[1024]); xg3 = bf2f(xpr[1536]);
            }
            float a0 = 0.f, a1 = 0.f, a2 = 0.f, a3 = 0.f;
            if (t > 0) {
                const unsigned* src = hpk + ((size_t)(bt - 1) << 8);
                unsigned u;
                do {
                    u = __hip_atomic_load(src + tid, __ATOMIC_RELAXED, __HIP_MEMORY_SCOPE_AGENT);
                } while (u == 0xFFFFFFFFu);
                unsigned* hbuf = hs2 + ((t - 1) & 1) * 272;
                hbuf[skslot] = u;
                __syncthreads();  // barriers #2..#128
                const unsigned* hp2 = hbuf + kq * 68;
#pragma unroll
                for (int q = 0; q < 32; q++) {
                    uint4 A = wifp[q << 8];
                    uint4 B = wgo[q];
                    unsigned p0 = hp2[q << 1];
                    unsigned p1 = hp2[(q << 1) + 1];
                    a0 = fdot2u(A.x, p0, a0); a0 = fdot2u(A.y, p1, a0);
                    a1 = fdot2u(A.z, p0, a1); a1 = fdot2u(A.w, p1, a1);
                    a2 = fdot2u(B.x, p0, a2); a2 = fdot2u(B.y, p1, a2);
                    a3 = fdot2u(B.z, p0, a3); a3 = fdot2u(B.w, p1, a3);
                }
#pragma unroll
                for (int off = 1; off <= 2; off <<= 1) {
                    a0 += __shfl_xor(a0, off);
                    a1 += __shfl_xor(a1, off);
                    a2 += __shfl_xor(a2, off);
                    a3 += __shfl_xor(a3, off);
                }
            }
            float h = 0.f;
            if (kq == 0) {
                float g0 = xg0 + a0, g1 = xg1 + a1, g2 = xg2 + a2, g3 = xg3 + a3;
                c = fsigm(g1) * c + fsigm(g0) * ftanh(g2);
                h = fsigm(g3) * ftanh(c);
                h_all[(size_t)bt * 512 + j_global] = f2bf(h);
            }
            float hp = __shfl_xor(h, 4);  // leader jj even <- h of jj+1
            if (kq == 0 && (jj & 1) == 0) {
                unsigned u = pkh2(h, hp);
                __hip_atomic_store(hpk + ((size_t)bt << 8) + ((bid >> 5) << 5) + ((tid >> 6) << 3) + (jj >> 1),
                                   u, __ATOMIC_RELAXED, __HIP_MEMORY_SCOPE_AGENT);
            }
        }
    } else {
        // ================= pack path (waves 4-7): 40 v-rows per block =================
        int ptid = tid - 256;           // 0..255
        int pw = ptid >> 6, pl = ptid & 63;
        int v0 = bid * 40;              // 256 blocks x 40 = 10240 = VP
        __syncthreads();  // barrier #1
        for (int t = 1; t < 128; t++) {
            if (t <= 20) {
                // Pb: 2 rows/chunk, 1024 elems = 256 float4 units
                int u = ptid;
                int row = v0 + 2 * (t - 1) + (u >> 7);
                int c4 = u & 127;
                ushort4 o = make_ushort4(0, 0, 0, 0);
                if (row < VV) {
                    float4 v = *(const float4*)(w_prior + (size_t)row * 512 + c4 * 4);
                    o = make_ushort4(f2bf(v.x), f2bf(v.y), f2bf(v.z), f2bf(v.w));
                }
                *(ushort4*)(Pb + (size_t)row * 512 + c4 * 4) = o;
            } else if (t <= 30) {
                // Gb: 4 rows/chunk, 1024 elems
                int u = ptid;
                int row = v0 + 4 * (t - 21) + (u >> 6);
                int c4 = u & 63;
                ushort4 o = make_ushort4(0, 0, 0, 0);
                if (row < VV) {
                    float4 v = *(const float4*)(w_gen2 + (size_t)row * 256 + c4 * 4);
                    o = make_ushort4(f2bf(v.x), f2bf(v.y), f2bf(v.z), f2bf(v.w));
                }
                *(ushort4*)(Gb + (size_t)row * 256 + c4 * 4) = o;
            } else if (t <= 40) {
                // Qb + cv: one v per wave per chunk (4 v/chunk)
                int v = v0 + 4 * (t - 31) + pw;
                float ct = 0.f;
                if (v < VV) {
#pragma unroll
                    for (int pass = 0; pass < 4; pass++) {
                        int k = pass * 64 + pl;
                        float mu = emb[(size_t)v * 512 + k];
                        float sg = softplus_b(emb[(size_t)v * 512 + 256 + k]);
                        float iv = 0.5f / (sg * sg);
                        Qb[((size_t)v << 9) + k] = f2bf(2.f * iv * mu);
                        Qb[((size_t)v << 9) + 256 + k] = f2bf(-iv);
                        ct += -HLOG2PI - logf(sg) - mu * mu * iv;
                    }
                } else {
#pragma unroll
                    for (int pass = 0; pass < 4; pass++) {
                        int k = pass * 64 + pl;
                        Qb[((size_t)v << 9) + k] = 0;
                        Qb[((size_t)v << 9) + 256 + k] = 0;
                    }
                }
#pragma unroll
                for (int off = 1; off <= 32; off <<= 1) ct += __shfl_xor(ct, off);
                if (pl == 0) cv[v] = (v < VV) ? ct : 0.f;
            }
            __syncthreads();  // barriers #2..#128
        }
    }
}

// ---------------- 4a) cast weights -> bf16 row-major (w_ih only now) ----------------
__global__ __launch_bounds__(256) void k_pack_w(const float* __restrict__ src,
                                                ushort* __restrict__ dst, int kshift) {
    int o = blockIdx.x * 256 + threadIdx.x;  // one ushort4 unit
    int c = o & ((1 << kshift) - 1);
    int r = o >> kshift;
    ushort4 u = make_ushort4(0, 0, 0, 0);
    if (r < VV) {
        float4 v = *(const float4*)(src + ((size_t)r << (kshift + 2)) + (c << 2));
        u = make_ushort4(f2bf(v.x), f2bf(v.y), f2bf(v.z), f2bf(v.w));
    }
    *(ushort4*)(dst + ((size_t)o << 2)) = u;
}

// ---------------- 6) fused scores v7: fixed-shift LSE for bounded comps ----------------
__global__ __launch_bounds__(512, 2) void k_scores(
    const ushort* __restrict__ hb, const ushort* __restrict__ zb,
    const ushort* __restrict__ Pb, const ushort* __restrict__ Qb,
    const ushort* __restrict__ Gb, const float* __restrict__ cv,
    const float* __restrict__ b_prior, const float* __restrict__ b_gen,
    float* __restrict__ part) {
    extern __shared__ ushort sm[];
    ushort* hT = sm;           // [kc 16][64 rows][32], swizzled granules = 64 KB
    ushort* fzT = sm + 32768;  // [kc 16][64 rows][32]: kc<8 z, kc>=8 z^2 = 64 KB
    int tid = threadIdx.x;
    int vs = blockIdx.x & 7;
    int mb = blockIdx.x >> 3;
    int bt0 = mb << 6;
    int vbase = vs * 1280;
    // stage h tile (64 x 512 bf16): pure 16B copies
    for (int i = tid; i < 4096; i += 512) {
        int quad = i & 3, row = (i >> 2) & 63, kc = i >> 8;
        uint4 v = *(const uint4*)(hb + (size_t)(bt0 + row) * 512 + kc * 32 + quad * 8);
        int g = (((row << 2) + (quad ^ (row & 3))) ^ (((row >> 2) & 1) << 2));
        *(uint4*)(hT + kc * 2048 + g * 8) = v;
    }
    // stage z (copy) + z^2 (bsq once per granule)
    for (int i = tid; i < 2048; i += 512) {
        int quad = i & 3, row = (i >> 2) & 63, kc = i >> 8;  // kc 0..7
        uint4 v = *(const uint4*)(zb + (size_t)(bt0 + row) * 256 + kc * 32 + quad * 8);
        int g = (((row << 2) + (quad ^ (row & 3))) ^ (((row >> 2) & 1) << 2));
        *(uint4*)(fzT + kc * 2048 + g * 8) = v;
        bf16x8 sq = bsq(*(bf16x8*)&v);
        *(uint4*)(fzT + (kc + 8) * 2048 + g * 8) = *(uint4*)&sq;
    }
    __syncthreads();
    int w = tid >> 6, l = tid & 63;
    int quad = l >> 4, ln = l & 15;
    int nq = w;  // wave: ALL 64 rows x cols nq*32..+32 per nt group
    const bf16x8* hT8 = (const bf16x8*)hT;
    const bf16x8* fz8 = (const bf16x8*)fzT;
    const bf16x8* Pb8 = (const bf16x8*)Pb;
    const bf16x8* Qb8 = (const bf16x8*)Qb;
    const bf16x8* Gb8 = (const bf16x8*)Gb;
    // ms=0 row = ln; ms adds 16 rows => granule g0 + 64*ms (swizzle-consistent)
    int g0 = (((ln << 2) + (quad ^ (ln & 3))) ^ (((ln >> 2) & 1) << 2));
    float Ls[3][16], Lm1[16];
#pragma unroll
    for (int c = 0; c < 3; c++)
#pragma unroll
        for (int r = 0; r < 16; r++) Ls[c][r] = 0.f;
#pragma unroll
    for (int r = 0; r < 16; r++) Lm1[r] = -1e30f;
#pragma unroll 1
    for (int nt = 0; nt < 5; nt++) {
        int n0 = vbase + (nt << 8) + (nq << 5);
        int rb = (n0 + ln) << 6;  // Pb/Qb granule row base (ns adds 1024)
        int rg = (n0 + ln) << 5;  // Gb granule row base (ns adds 512)
        __builtin_amdgcn_s_setprio(1);
        // ---- chain A: prior logits, h (K=512) vs Pb ----
        f32x4 accA[4][2];
#pragma unroll
        for (int ms = 0; ms < 4; ms++) { accA[ms][0] = 0.f; accA[ms][1] = 0.f; }
#pragma unroll 2
        for (int kc = 0; kc < 16; kc++) {
            bf16x8 b0 = Pb8[rb + (kc << 2) + quad];
            bf16x8 b1 = Pb8[rb + 1024 + (kc << 2) + quad];
#pragma unroll
            for (int ms = 0; ms < 4; ms++) {
                bf16x8 a = hT8[(kc << 8) + g0 + (ms << 6)];
                accA[ms][0] = __builtin_amdgcn_mfma_f32_16x16x32_bf16(a, b0, accA[ms][0], 0, 0, 0);
                accA[ms][1] = __builtin_amdgcn_mfma_f32_16x16x32_bf16(a, b1, accA[ms][1], 0, 0, 0);
            }
        }
        __builtin_amdgcn_s_setprio(0);
        // ---- epilogue A: fixed-shift sum for comp0; fold u1+cv into accB init ----
        f32x4 accB[4][2];
#pragma unroll
        for (int ns = 0; ns < 2; ns++) {
            int col = n0 + (ns << 4) + ln;
            bool ok = col < VV;
            float bpv = ok ? b_prior[col] : 0.f;
            float cvv = ok ? cv[col] : 0.f;
#pragma unroll
            for (int ms = 0; ms < 4; ms++)
#pragma unroll
                for (int r = 0; r < 4; r++) {
                    int r16 = (ms << 2) + r;
                    float u1 = ok ? accA[ms][ns][r] + bpv : -1e30f;
                    Ls[0][r16] += __expf(u1 - FMSHIFT);  // exp(-1e30)=0 for pads
                    accB[ms][ns][r] = ok ? u1 + cvv : -1e30f;  // pad Qb rows are 0
                }
        }
        __builtin_amdgcn_s_setprio(1);
        // ---- chain B: z (kc 0..7) + z^2 (kc 8..15) vs Qb ----
#pragma unroll 2
        for (int kc = 0; kc < 16; kc++) {
            bf16x8 bq0 = Qb8[rb + (kc << 2) + quad];
            bf16x8 bq1 = Qb8[rb + 1024 + (kc << 2) + quad];
#pragma unroll
            for (int ms = 0; ms < 4; ms++) {
                bf16x8 a = fz8[(kc << 8) + g0 + (ms << 6)];
                accB[ms][0] = __builtin_amdgcn_mfma_f32_16x16x32_bf16(a, bq0, accB[ms][0], 0, 0, 0);
                accB[ms][1] = __builtin_amdgcn_mfma_f32_16x16x32_bf16(a, bq1, accB[ms][1], 0, 0, 0);
            }
        }
        __builtin_amdgcn_s_setprio(0);
        // ---- epilogue B: online LSE (comp1 has unbounded-scale lp) ----
#pragma unroll
        for (int ns = 0; ns < 2; ns++)
#pragma unroll
            for (int ms = 0; ms < 4; ms++)
#pragma unroll
                for (int r = 0; r < 4; r++) {
                    int r16 = (ms << 2) + r;
                    float u2 = accB[ms][ns][r];
                    float nm = fmaxf(Lm1[r16], u2);
                    Ls[1][r16] = Ls[1][r16] * __expf(Lm1[r16] - nm) + __expf(u2 - nm);
                    Lm1[r16] = nm;
                }
        // ---- chain C: gen logits, z (K=256) vs Gb ----
        f32x4 accC[4][2];
#pragma unroll
        for (int ns = 0; ns < 2; ns++) {
            int col = n0 + (ns << 4) + ln;
            bool ok = col < VV;
            float bgv = ok ? b_gen[col] : -1e30f;  // pad Gb rows are 0
#pragma unroll
            for (int ms = 0; ms < 4; ms++) accC[ms][ns] = bgv;
        }
        __builtin_amdgcn_s_setprio(1);
#pragma unroll 2
        for (int kc = 0; kc < 8; kc++) {
            bf16x8 bg0 = Gb8[rg + (kc << 2) + quad];
            bf16x8 bg1 = Gb8[rg + 512 + (kc << 2) + quad];
#pragma unroll
            for (int ms = 0; ms < 4; ms++) {
                bf16x8 a = fz8[(kc << 8) + g0 + (ms << 6)];
                accC[ms][0] = __builtin_amdgcn_mfma_f32_16x16x32_bf16(a, bg0, accC[ms][0], 0, 0, 0);
                accC[ms][1] = __builtin_amdgcn_mfma_f32_16x16x32_bf16(a, bg1, accC[ms][1], 0, 0, 0);
            }
        }
        __builtin_amdgcn_s_setprio(0);
        // ---- epilogue C: fixed-shift sum for comp2 ----
#pragma unroll
        for (int ns = 0; ns < 2; ns++)
#pragma unroll
            for (int ms = 0; ms < 4; ms++)
#pragma unroll
                for (int r = 0; r < 4; r++)
                    Ls[2][(ms << 2) + r] += __expf(accC[ms][ns][r] - FMSHIFT);
    }
    // merge across the 16 col-lanes (same rows; xor of low-4 bits keeps quad)
#pragma unroll
    for (int off = 1; off <= 8; off <<= 1)
#pragma unroll
        for (int r16 = 0; r16 < 16; r16++) {
            Ls[0][r16] += __shfl_xor(Ls[0][r16], off);
            Ls[2][r16] += __shfl_xor(Ls[2][r16], off);
            float mo = __shfl_xor(Lm1[r16], off);
            float so = __shfl_xor(Ls[1][r16], off);
            float nm = fmaxf(Lm1[r16], mo);
            Ls[1][r16] = Ls[1][r16] * __expf(Lm1[r16] - nm) + so * __expf(mo - nm);
            Lm1[r16] = nm;
        }
    // block-level merge across the 8 wave column-slices (staging LDS is dead now)
    __syncthreads();
    float* bs = (float*)sm;   // [3][8 w][64 rows] = 1536
    float* bm = bs + 1536;    // [8 w][64 rows] = 512 (comp1 max only)
    if (ln == 0) {
#pragma unroll
        for (int r16 = 0; r16 < 16; r16++) {
            int row = ((r16 >> 2) << 4) + (quad << 2) + (r16 & 3);
#pragma unroll
            for (int c = 0; c < 3; c++) bs[(c * 8 + w) * 64 + row] = Ls[c][r16];
            bm[w * 64 + row] = Lm1[r16];
        }
    }
    __syncthreads();
    if (tid < 192) {
        int c = tid >> 6, row = tid & 63;
        float M, S;
        if (c == 1) {
            M = -1e30f; S = 0.f;
#pragma unroll
            for (int q = 0; q < 8; q++) {
                float m = bm[q * 64 + row];
                float s = bs[(8 + q) * 64 + row];
                float Mn = fmaxf(M, m);
                S = S * __expf(M - Mn) + s * __expf(m - Mn);
                M = Mn;
            }
        } else {
            M = FMSHIFT; S = 0.f;
#pragma unroll
            for (int q = 0; q < 8; q++) S += bs[(c * 8 + q) * 64 + row];
        }
        part[(vs * 6 + c * 2) * 4096 + bt0 + row] = M;
        part[(vs * 6 + c * 2 + 1) * 4096 + bt0 + row] = S;
    }
}

// ---------------- 8) finalize (merge 8 V-split partials), 2-stage ----------------
__device__ __forceinline__ float lse8(const float* __restrict__ part, int comp, int bt) {
    float M = -1e30f, S = 0.f;
#pragma unroll
    for (int vsi = 0; vsi < 8; vsi++) {
        float m = part[(vsi * 6 + comp) * 4096 + bt];
        float s = part[(vsi * 6 + comp + 1) * 4096 + bt];
        float Mn = fmaxf(M, m);
        S = S * __expf(M - Mn) + s * __expf(m - Mn);
        M = Mn;
    }
    return M + logf(S);
}

// stage 1: 32 blocks x 128 threads — block bid handles batch b = bid
__global__ void k_final1(const float* __restrict__ part, const float* __restrict__ qz,
                         const float* __restrict__ gxv, const int* __restrict__ x_sl,
                         float* __restrict__ psum) {
    int bid = blockIdx.x;
    int tid = threadIdx.x;
    int bt = (bid << 7) + tid;
    float S = 0.f;
    if (tid < x_sl[bid]) {
        float lse1 = lse8(part, 0, bt);
        float lse2 = lse8(part, 2, bt);
        float lse3 = lse8(part, 4, bt);
        float p_z = lse2 - lse1;
        float kl = qz[bt] - p_z;
        float px = gxv[bt] - lse3;
        S = px - kl;
    }
    __shared__ float red[128];
    red[tid] = S;
    __syncthreads();
    for (int s = 64; s > 0; s >>= 1) {
        if (tid < s) red[tid] += red[tid + s];
        __syncthreads();
    }
    if (tid == 0) psum[bid] = red[0];
}

// stage 2: 1 block x 64 threads — reduce 32 partials, divide, negate
__global__ void k_final2(const float* __restrict__ psum, const int* __restrict__ x_sl,
                         float* __restrict__ out) {
    int tid = threadIdx.x;
    float s = (tid < 32) ? psum[tid] : 0.f;
#pragma unroll
    for (int off = 32; off >= 1; off >>= 1) s += __shfl_down(s, off);
    if (tid == 0) {
        int sl = 0;
        for (int b = 0; b < 32; b++) sl += x_sl[b];
        out[0] = -(s / (float)sl);
    }
}

extern "C" void kernel_launch(void* const* d_in, const int* in_sizes, int n_in,
                              void* d_out, int out_size, void* d_ws, size_t ws_size,
                              hipStream_t stream) {
    const int* x = (const int*)d_in[0];
    const int* x_sl = (const int*)d_in[1];
    const float* eps = (const float*)d_in[2];
    const float* emb = (const float*)d_in[3];
    const float* w_ih = (const float*)d_in[4];
    const float* w_hh = (const float*)d_in[5];
    const float* b_ih = (const float*)d_in[6];
    const float* b_hh = (const float*)d_in[7];
    const float* w_prior = (const float*)d_in[8];
    const float* b_prior = (const float*)d_in[9];
    const float* w_gen = (const float*)d_in[10];
    const float* b_gen = (const float*)d_in[11];

    float* ws = (float*)d_ws;
    float* qz = ws + 1048576;
    ushort* hb = (ushort*)(ws + 1052672);            // BT*H bf16 = 4 MB
    ushort* zb = (ushort*)(ws + 1052672 + 1048576);  // BT*K bf16 = 2 MB
    float* gx = ws + 3149824;
    float* region = ws + 3252224;
    ushort* xpb = (ushort*)region;                   // BT*2048 bf16 = 16.8 MB
    uint4* wpIF = (uint4*)(region + 4194304);
    uint4* wpGO = wpIF + 65536;
    unsigned* hpk = (unsigned*)(region + 4718592);   // 1048576 dwords
    ushort* wb = (ushort*)(region + 5767168);        // w_ih bf16, 1 MB
    ushort* Pb = (ushort*)(region + 6029312);
    ushort* Qb = (ushort*)(region + 8650752);
    ushort* Gb = (ushort*)(region + 11272192);
    float* part = region + 12582912;                 // 8*6*4096
    float* psum = region + 12779520;                 // 32 floats
    float* cv = region + 12779552;                   // 10240 floats

    k_embed<<<4096, 256, 0, stream>>>(x, x_sl, eps, emb, w_gen, b_gen, zb, qz, gx);
    k_pack_w<<<512, 256, 0, stream>>>(w_ih, wb, 6);  // w_ih -> bf16 (2048 rows < VV)
    k_xpm<<<512, 512, 0, stream>>>(zb, wb, b_ih, b_hh, xpb);
    k_wpack2<<<dim3(256, 2), 256, 0, stream>>>(w_hh, wpIF, wpGO);
    hipMemsetAsync(hpk, 0xFF, 4194304, stream);  // sentinel: f16 NaN pairs
    {
        hipFuncSetAttribute((const void*)k_lstm, hipFuncAttributeMaxDynamicSharedMemorySize, 133248);
        void* args[] = {(void*)&xpb, (void*)&wpIF, (void*)&wpGO, (void*)&hb, (void*)&hpk,
                        (void*)&w_prior, (void*)&w_gen, (void*)&emb,
                        (void*)&Pb, (void*)&Qb, (void*)&Gb, (void*)&cv};
        hipLaunchCooperativeKernel((const void*)k_lstm, dim3(256), dim3(512), args, 133248, stream);
    }
    hipFuncSetAttribute((const void*)k_scores, hipFuncAttributeMaxDynamicSharedMemorySize, 131072);
    k_scores<<<512, 512, 131072, stream>>>(hb, zb, Pb, Qb, Gb, cv, b_prior, b_gen, part);
    k_final1<<<32, 128, 0, stream>>>(part, qz, gx, x_sl, psum);
    k_final2<<<1, 64, 0, stream>>>(psum, x_sl, (float*)d_out);
}